// Round 7
// baseline (257.640 us; speedup 1.0000x reference)
//
#include <hip/hip_runtime.h>
#include <hip/hip_bf16.h>
#include <stdint.h>

#define B_SZ   2048
#define DDATA  768
#define NSAE   128
#define NJK    4096   // NSAE*32
#define KA2    4352   // NJK + 128 (acts0) + 128 (gate)
#define SPLITK 4
#define KC2    1088   // KA2 / SPLITK (17 x BK=64)
#define B2TB   816    // B2T rider blocks (68 rb x 12 dbk) inside GEMM1 launch
#define G1TILES 512   // 16 by x 32 bx (128x128 tiles)

typedef unsigned short u16;
typedef short bf16x8 __attribute__((ext_vector_type(8)));
typedef float f32x4  __attribute__((ext_vector_type(4)));

static __device__ __forceinline__ u16 f2bf(float f) {
  __hip_bfloat16 h = __float2bfloat16(f);
  return *reinterpret_cast<u16*>(&h);
}

static __device__ __forceinline__ void gload16(const u16* g, u16* l) {
  __builtin_amdgcn_global_load_lds(
      (const __attribute__((address_space(1))) unsigned int*)g,
      (__attribute__((address_space(3))) unsigned int*)l,
      16, 0, 0);
}

// ======== k_front: gate/acts0 + W1T/cv + counter-zero ========
// blocks   0..511 : gate/acts0: 4 rows/block, 4 waves split d into 192-chunks
// blocks 512..895 : expert j transpose We1[j]->W1T, dbk seg-split 3x;
//                   cv partials to cvp[seg] (summed in GEMM1 preload)
// block  896      : zero the G1 split-K tile counters (re-poison-safe)
__global__ __launch_bounds__(256) void k_front(const float* __restrict__ x,
                                               const float* __restrict__ We0,
                                               const float* __restrict__ be0,
                                               const float* __restrict__ bd0,
                                               const float* __restrict__ We1,
                                               const float* __restrict__ bd1,
                                               const float* __restrict__ be1,
                                               u16* __restrict__ W1T,
                                               float* __restrict__ cvp,
                                               u16* __restrict__ xb,
                                               u16* __restrict__ A2,
                                               unsigned* __restrict__ cnt) {
  __shared__ float smem[6280];                  // 25.1 KB, shared by branches
  const int bid = blockIdx.x, t = threadIdx.x;
  if (bid < 512) {
    // ---------------- gate branch: rows b0..b0+3 ----------------
    const int b0 = bid * 4;
    float* xs   = smem;                         // [4][768] = x - bd0
    float* part = smem + 3072;                  // [4 waves][4 rows][128]
    float* wqp  = smem + 5120;                  // [4 waves][128] ||We0||^2 partials
    float* xns  = smem + 5632;                  // [4] row norms
#pragma unroll
    for (int i = 0; i < 3; ++i) {
      int idx = t + i * 256;                    // 768 float4
      int r = idx / 192, c4 = idx % 192;
      size_t go = (size_t)(b0 + r) * DDATA + c4 * 4;
      float4 v = *(const float4*)&x[go];
      ushort4 o;
      o.x = f2bf(v.x); o.y = f2bf(v.y); o.z = f2bf(v.z); o.w = f2bf(v.w);
      *(ushort4*)&xb[go] = o;                   // fused x cast for GEMM1
      float4 b4 = *(const float4*)&bd0[c4 * 4];
      v.x -= b4.x; v.y -= b4.y; v.z -= b4.z; v.w -= b4.w;
      *(float4*)&xs[r * DDATA + c4 * 4] = v;
    }
    __syncthreads();
    const int ln = t & 63, w = t >> 6;
    {                                           // row norm: wave w owns row w
      float a = 0.f;
#pragma unroll
      for (int q = 0; q < 12; ++q) { float xv = xs[w * DDATA + ln + q * 64]; a += xv * xv; }
#pragma unroll
      for (int sh = 32; sh; sh >>= 1) a += __shfl_xor(a, sh, 64);
      if (ln == 0) xns[w] = a;
    }
    const int j0 = ln * 2;                      // 2 experts per lane
    // wave w accumulates d in [w*192, w*192+192) for ALL 4 rows (partials)
    float a00=0.f,a01=0.f,a10=0.f,a11=0.f,a20=0.f,a21=0.f,a30=0.f,a31=0.f;
    float wq0=0.f, wq1=0.f;
    const int dbase = w * 192;
    for (int d = dbase; d < dbase + 192; d += 4) {
      float4 xv0 = *(const float4*)&xs[0 * DDATA + d];   // wave-uniform bcast
      float4 xv1 = *(const float4*)&xs[1 * DDATA + d];
      float4 xv2 = *(const float4*)&xs[2 * DDATA + d];
      float4 xv3 = *(const float4*)&xs[3 * DDATA + d];
#pragma unroll
      for (int dd = 0; dd < 4; ++dd) {
        float2 w2 = *(const float2*)&We0[(size_t)(d + dd) * 128 + j0];
        float x0 = ((const float*)&xv0)[dd], x1 = ((const float*)&xv1)[dd];
        float x2 = ((const float*)&xv2)[dd], x3 = ((const float*)&xv3)[dd];
        a00 += x0 * w2.x; a01 += x0 * w2.y;
        a10 += x1 * w2.x; a11 += x1 * w2.y;
        a20 += x2 * w2.x; a21 += x2 * w2.y;
        a30 += x3 * w2.x; a31 += x3 * w2.y;
        wq0 += w2.x * w2.x; wq1 += w2.y * w2.y;
      }
    }
    *(float2*)&part[(w * 4 + 0) * 128 + j0] = make_float2(a00, a01);
    *(float2*)&part[(w * 4 + 1) * 128 + j0] = make_float2(a10, a11);
    *(float2*)&part[(w * 4 + 2) * 128 + j0] = make_float2(a20, a21);
    *(float2*)&part[(w * 4 + 3) * 128 + j0] = make_float2(a30, a31);
    *(float2*)&wqp[w * 128 + j0] = make_float2(wq0, wq1);
    __syncthreads();
    // finalize: wave w owns row w; lane handles experts j0, j0+1
    float p0 = be0[j0], p1 = be0[j0 + 1];
    float wn0 = 0.f, wn1 = 0.f;
#pragma unroll
    for (int q = 0; q < 4; ++q) {
      float2 pr = *(const float2*)&part[(q * 4 + w) * 128 + j0];
      p0 += pr.x; p1 += pr.y;
      float2 wr2 = *(const float2*)&wqp[q * 128 + j0];
      wn0 += wr2.x; wn1 += wr2.y;
    }
    const float sx = sqrtf(xns[w]);
    const float tau0 = 1e-4f * sx * sqrtf(wn0);
    const float tau1 = 1e-4f * sx * sqrtf(wn1);
    const int bb = b0 + w;
    const size_t row = (size_t)bb * KA2;
    unsigned pk = (unsigned)f2bf(p0 > 0.f ? p0 : 0.f) |
                  ((unsigned)f2bf(p1 > 0.f ? p1 : 0.f) << 16);
    unsigned gk = (p0 > 0.f ? 0x3F80u : 0u) | (p1 > 0.f ? 0x3F800000u : 0u);
    *(unsigned*)&A2[row + NJK + j0]       = pk;
    *(unsigned*)&A2[row + NJK + 128 + j0] = gk;
    // fp32 sign uncertain -> whole wave cooperates on exact fp64 recompute
#pragma unroll
    for (int c = 0; c < 2; ++c) {
      float pv = c ? p1 : p0;
      float tv = c ? tau1 : tau0;
      unsigned long long mask = __ballot(fabsf(pv) <= tv);
      while (mask) {
        int src = (int)__builtin_ctzll(mask);
        mask &= mask - 1;
        int jj = src * 2 + c;
        double acc = 0.0;
#pragma unroll
        for (int q = 0; q < 12; ++q) {
          int d = ln + q * 64;
          acc += (double)(x[(size_t)bb * DDATA + d] - bd0[d]) *
                 (double)We0[(size_t)d * 128 + jj];
        }
#pragma unroll
        for (int sh = 32; sh; sh >>= 1) acc += __shfl_xor(acc, sh, 64);
        if (ln == src) {
          double pd = acc + (double)be0[jj];
          A2[row + NJK + jj]       = f2bf(pd > 0.0 ? (float)pd : 0.f);
          A2[row + NJK + 128 + jj] = (pd > 0.0) ? (u16)0x3F80 : (u16)0;
        }
      }
    }
  } else if (bid < 896) {
    // ---------------- We1 transpose + cv partials (j, seg) ----------------
    const int e = bid - 512;
    const int j = e & 127, seg = e >> 7;        // seg 0..2 -> dbk seg*4..seg*4+3
    float* ts  = smem;                          // 64*33
    float* bds = smem + 64 * 33;                // 64
    float* red = smem + 64 * 33 + 64;           // 8*32
    const int k = t & 31, g = t >> 5;
    float cacc = 0.f;
    for (int db = seg * 4; db < seg * 4 + 4; ++db) {
      const float* src = We1 + (size_t)j * 24576 + db * 2048;  // 64 d x 32 k
#pragma unroll
      for (int i = 0; i < 8; ++i) {
        int ee = t + i * 256;
        ts[(ee >> 5) * 33 + (ee & 31)] = src[ee];
      }
      if (t < 64) bds[t] = bd1[(size_t)j * DDATA + db * 64 + t];
      __syncthreads();
#pragma unroll
      for (int i = 0; i < 8; ++i) {
        int ee = t + i * 256;
        int kk = ee >> 6, d = ee & 63;
        W1T[(size_t)(j * 32 + kk) * DDATA + db * 64 + d] = f2bf(ts[d * 33 + kk]);
      }
#pragma unroll
      for (int q = 0; q < 8; ++q) {
        int d = g + 8 * q;
        cacc += ts[d * 33 + k] * bds[d];
      }
      __syncthreads();
    }
    red[g * 32 + k] = cacc;
    __syncthreads();
    if (g == 0) {
      float s = 0.f;
#pragma unroll
      for (int q = 0; q < 8; ++q) s += red[q * 32 + k];
      cvp[seg * 4096 + j * 32 + k] = (seg == 0 ? be1[j * 32 + k] : 0.f) - s;
    }
  } else {
    // ---------------- zero G1 tile counters ----------------
    cnt[t] = 0u;
    cnt[t + 256] = 0u;
  }
}

// ------ GEMM: C = A[M,K] * B^T[N,K], bf16 MFMA 16x16x32, BK=64, XOR-swizzled LDS ------
// Single-buffer 2-phase loop with __syncthreads (proven-correct sync).
// Wall model (R2-R6 calibrated): wall ~ staged_traffic/(bytes_per_step x co_res).
// EPI=1: 128x128 tile + SPLITK2 -> factor 3.07->1.53 (half panel traffic, 4/CU).
//        Both split blocks store fp32 partials; last-arriver (tile counter)
//        fences, reads the other slot, adds, runs relu/gate/pack epilogue.
//        XCD-chunked decode puts both splits of a tile ADJACENT (same XCD L2);
//        __threadfence() release/acquire keeps it correct regardless.
// EPI=1 also carries B2TB rider blocks (h < B2TB) building B2T during stalls.
// EPI=2: split-K fp32 partials to outF (reduced by k_reduce), unchanged.
template<int BM, int BN, int EPI>
__global__ __launch_bounds__(256) void k_gemm(const u16* __restrict__ A,
                                              const u16* __restrict__ Bm,
                                              int K, int Kc,
                                              float* __restrict__ outF,
                                              u16* __restrict__ A2,
                                              const float* __restrict__ cvec,
                                              const float* __restrict__ Wd1,
                                              const float* __restrict__ Wd0,
                                              const float* __restrict__ bd1,
                                              u16* __restrict__ B2Tp,
                                              float* __restrict__ partG1,
                                              unsigned* __restrict__ cnt) {
  constexpr int WM = BM / 32, WN = BN / 32;
  __shared__ __align__(16) u16 AsBs[(BM + BN) * 64];   // As | Bs
  __shared__ u16 gate_s[BM * 4];
  __shared__ float cv_s[BN];
  __shared__ unsigned who_s;
  const int tid = threadIdx.x;
  const int h = blockIdx.x;

  if (EPI == 1 && h < B2TB) {
    // ------- B2T rider: [W_dec1 ; W_dec0 ; b_dec1]^T, 68 rb x 12 dbk -------
    float* fsm = (float*)&AsBs[0];              // 32.8KB >= 64*65*4
    const int rb = h / 12, dbk = h % 12;
    const float* src; int r0, base;
    if (rb < 64)      { src = Wd1; r0 = rb * 64;        base = 0;    }
    else if (rb < 66) { src = Wd0; r0 = (rb - 64) * 64; base = 4096; }
    else              { src = bd1; r0 = (rb - 66) * 64; base = 4224; }
    const int d0 = dbk * 64;
#pragma unroll
    for (int i = 0; i < 16; ++i) {
      int ee = tid + i * 256;
      int ri = ee >> 6, di = ee & 63;
      fsm[ri * 65 + di] = src[(size_t)(r0 + ri) * DDATA + d0 + di];
    }
    __syncthreads();
#pragma unroll
    for (int i = 0; i < 16; ++i) {
      int ee = tid + i * 256;
      int di = ee >> 6, ri = ee & 63;
      B2Tp[(size_t)(d0 + di) * KA2 + base + r0 + ri] = f2bf(fsm[ri * 65 + di]);
    }
    return;
  }

  int bx, by, bz;
  if (EPI == 1) {
    // 1024 gemm blocks = 8 XCD-chunks of 128 = 64 tiles x 2 splits.
    // Splits of a tile are ADJACENT in a chunk -> same XCD (shared L2).
    const int hg = h - B2TB;                    // B2TB%8==0 keeps XCD = h%8
    const int l = (hg & 7) * 128 + (hg >> 3);   // bijective: 1024 = 8*128
    const int g2 = l >> 7;                      // chunk on XCD
    const int w = l & 127;
    const int tl = w >> 1;                      // tile within chunk [0,64)
    bz = w & 1;                                 // split
    by = tl >> 2;                               // [0,16)
    bx = (g2 << 2) + (tl & 3);                  // [0,32): 4 B-panels/XCD
  } else {
    const int l = (h & 7) * 96 + (h >> 3);      // bijective: 768 = 8*96
    bx = l >> 7; const int r2 = l & 127; bz = r2 >> 5; by = r2 & 31;
  }
  const int kbase = bz * Kc;
  const u16* Ab = A  + (size_t)(by * BM) * K;
  const u16* Bb = Bm + (size_t)(bx * BN) * K;
  const int wave = tid >> 6, lane = tid & 63;
  const int wr = wave >> 1, wc = wave & 1;
  const int m0 = wr * (BM / 2), n0 = wc * (BN / 2);
  const int lm = lane & 15, qd = lane >> 4;
  u16* As = &AsBs[0];
  u16* Bs = &AsBs[BM * 64];

  if (EPI == 1) {
    // preload epilogue data up front (used only by the last-arriver)
    for (int e = tid; e < BM * 4; e += 256) {
      int r = e >> 2, q = e & 3;
      gate_s[e] = A2[(size_t)(by * BM + r) * KA2 + NJK + 128 + bx * 4 + q];
    }
    for (int e = tid; e < BN; e += 256)
      cv_s[e] = cvec[bx * BN + e] + cvec[4096 + bx * BN + e] + cvec[8192 + bx * BN + e];
  }

  f32x4 acc[WM][WN];
  const f32x4 zero = {0.f, 0.f, 0.f, 0.f};
  for (int mi = 0; mi < WM; ++mi)
    for (int ni = 0; ni < WN; ++ni) acc[mi][ni] = zero;

  for (int k0 = kbase; k0 < kbase + Kc; k0 += 64) {
#pragma unroll
    for (int i = 0; i < BM / 32; ++i) {
      int id = tid + 256 * i;
      int row = id >> 3, u = id & 7;
      gload16(Ab + (size_t)row * K + k0 + ((u ^ (row & 7)) * 8), &As[id * 8]);
    }
#pragma unroll
    for (int i = 0; i < BN / 32; ++i) {
      int id = tid + 256 * i;
      int row = id >> 3, u = id & 7;
      gload16(Bb + (size_t)row * K + k0 + ((u ^ (row & 7)) * 8), &Bs[id * 8]);
    }
    __syncthreads();
#pragma unroll
    for (int s = 0; s < 2; ++s) {
      const int swz = ((s << 2) + qd) ^ (lm & 7);
      bf16x8 af[WM], bfv[WN];
#pragma unroll
      for (int mi = 0; mi < WM; ++mi)
        af[mi] = *(const bf16x8*)&As[(m0 + mi * 16 + lm) * 64 + swz * 8];
#pragma unroll
      for (int ni = 0; ni < WN; ++ni)
        bfv[ni] = *(const bf16x8*)&Bs[(n0 + ni * 16 + lm) * 64 + swz * 8];
#pragma unroll
      for (int mi = 0; mi < WM; ++mi)
#pragma unroll
        for (int ni = 0; ni < WN; ++ni)
          acc[mi][ni] = __builtin_amdgcn_mfma_f32_16x16x32_bf16(af[mi], bfv[ni],
                                                                acc[mi][ni], 0, 0, 0);
    }
    __syncthreads();
  }

  const int rb = qd * 4;
  if (EPI == 1) {
    // ---- split-K handoff: store my partial, last arriver reduces ----
    const int tileid = by * 32 + bx;
    float* myp = partG1 + ((size_t)(bz * G1TILES + tileid)) * (BM * BN);
#pragma unroll
    for (int mi = 0; mi < WM; ++mi)
#pragma unroll
      for (int ni = 0; ni < WN; ++ni)
#pragma unroll
        for (int r = 0; r < 4; ++r) {
          int ml = m0 + mi * 16 + rb + r;
          int nl = n0 + ni * 16 + lm;
          myp[ml * BN + nl] = acc[mi][ni][r];
        }
    __syncthreads();                            // drains stores (vmcnt 0)
    if (tid == 0) {
      __threadfence();                          // release: partial visible
      who_s = atomicAdd(&cnt[tileid], 1u);
    }
    __syncthreads();
    if (who_s == 0) return;                     // first arriver: done
    if (tid == 0) __threadfence();              // acquire before reading peer
    __syncthreads();
    const float* op = partG1 + ((size_t)((1 - bz) * G1TILES + tileid)) * (BM * BN);
#pragma unroll
    for (int mi = 0; mi < WM; ++mi) {
#pragma unroll
      for (int ni = 0; ni < WN; ++ni) {
#pragma unroll
        for (int r = 0; r < 4; ++r) {
          int ml = m0 + mi * 16 + rb + r;
          int nl = n0 + ni * 16 + lm;
          int gm = by * BM + ml;
          int gn = bx * BN + nl;
          float v = acc[mi][ni][r] + op[ml * BN + nl];
          v += cv_s[nl];
          v = v > 0.f ? v : 0.f;
          u16 gbit = gate_s[ml * 4 + (nl >> 5)];
          v = gbit ? v : 0.f;
          float vn = __shfl_xor(v, 1, 64);      // pack even/odd columns
          if ((lm & 1) == 0) {
            unsigned pk = (unsigned)f2bf(v) | ((unsigned)f2bf(vn) << 16);
            *(unsigned*)&A2[(size_t)gm * KA2 + gn] = pk;
          }
        }
      }
    }
  } else {
#pragma unroll
    for (int mi = 0; mi < WM; ++mi)
#pragma unroll
      for (int ni = 0; ni < WN; ++ni)
#pragma unroll
        for (int r = 0; r < 4; ++r) {
          int ml = m0 + mi * 16 + rb + r;
          int nl = n0 + ni * 16 + lm;
          int gm = by * BM + ml;
          int gn = bx * BN + nl;
          outF[((size_t)bz * B_SZ + gm) * DDATA + gn] = acc[mi][ni][r];
        }
  }
}

// ---------------- reduce split-K partials + bias ----------------
__global__ __launch_bounds__(256) void k_reduce(const float* __restrict__ part,
                                                const float* __restrict__ bias,
                                                float* __restrict__ out) {
  const int N4 = B_SZ * DDATA / 4;
  int i = blockIdx.x * 256 + threadIdx.x;
  const float4* p4 = (const float4*)part;
  float4 s = p4[i];
#pragma unroll
  for (int z = 1; z < SPLITK; ++z) {
    float4 t = p4[i + z * N4];
    s.x += t.x; s.y += t.y; s.z += t.z; s.w += t.w;
  }
  float4 b = ((const float4*)bias)[i % (DDATA / 4)];
  s.x += b.x; s.y += b.y; s.z += b.z; s.w += b.w;
  ((float4*)out)[i] = s;
}

extern "C" void kernel_launch(void* const* d_in, const int* in_sizes, int n_in,
                              void* d_out, int out_size, void* d_ws, size_t ws_size,
                              hipStream_t stream) {
  const float* x   = (const float*)d_in[0];
  const float* We0 = (const float*)d_in[1];
  const float* be0 = (const float*)d_in[2];
  const float* Wd0 = (const float*)d_in[3];
  const float* bd0 = (const float*)d_in[4];
  const float* We1 = (const float*)d_in[5];
  const float* be1 = (const float*)d_in[6];
  const float* Wd1 = (const float*)d_in[7];
  const float* bd1 = (const float*)d_in[8];
  float* out = (float*)d_out;

  uint8_t* ws = (uint8_t*)d_ws;
  size_t off = 0;
  auto carve = [&](size_t bytes) {
    uint8_t* p = ws + off;
    off += (bytes + 255) & ~(size_t)255;
    return p;
  };
  u16*      A2   = (u16*)carve((size_t)B_SZ * KA2 * 2);
  u16*      xb   = (u16*)carve((size_t)B_SZ * DDATA * 2);
  u16*      W1T  = (u16*)carve((size_t)NJK * DDATA * 2);
  u16*      B2T  = (u16*)carve((size_t)DDATA * KA2 * 2);
  float*    cvp  = (float*)carve((size_t)3 * NJK * 4);
  float*    part = (float*)carve((size_t)SPLITK * B_SZ * DDATA * 4);   // 25.2 MB
  float*    pG1  = (float*)carve((size_t)2 * G1TILES * 128 * 128 * 4); // 67.1 MB
  unsigned* cnt  = (unsigned*)carve((size_t)G1TILES * 4);

  // gate+acts0+fixup, W1T/cv, counter-zero (GEMM1's deps only)
  k_front <<<897, 256, 0, stream>>>(x, We0, be0, bd0, We1, bd1, be1,
                                    W1T, cvp, xb, A2, cnt);
  // GEMM1 (M=2048,N=4096,K=768): 128x128 tile, SPLITK2 counter epilogue,
  // 1024 gemm blocks (4/CU) + 816 B2T riders dispatched first
  k_gemm<128, 128, 1><<<B2TB + 1024, 256, 0, stream>>>(
      xb, W1T, DDATA, 384, nullptr, A2, cvp, Wd1, Wd0, bd1, B2T, pG1, cnt);
  // GEMM2 split-K (M=2048,N=768,K=4352): 64x128 tile, 768 blocks (3/CU)
  k_gemm<64, 128, 2><<<768, 256, 0, stream>>>(
      A2, B2T, KA2, KC2, part, nullptr, nullptr, nullptr, nullptr, nullptr,
      nullptr, nullptr, nullptr);
  k_reduce<<<1536, 256, 0, stream>>>(part, bd0, out);
}

// Round 8
// 163.739 us; speedup vs baseline: 1.5735x; 1.5735x over previous
//
#include <hip/hip_runtime.h>
#include <hip/hip_bf16.h>
#include <stdint.h>

#define B_SZ   2048
#define DDATA  768
#define NSAE   128
#define NJK    4096   // NSAE*32
#define KA2    4352   // NJK + 128 (acts0) + 128 (gate)
#define SPLITK 4
#define KC2    1088   // KA2 / SPLITK (17 x BK=64)
#define B2TB   816    // B2T rider blocks (68 rb x 12 dbk) inside GEMM1 launch

typedef unsigned short u16;
typedef short bf16x8 __attribute__((ext_vector_type(8)));
typedef float f32x4  __attribute__((ext_vector_type(4)));

static __device__ __forceinline__ u16 f2bf(float f) {
  __hip_bfloat16 h = __float2bfloat16(f);
  return *reinterpret_cast<u16*>(&h);
}

static __device__ __forceinline__ void gload16(const u16* g, u16* l) {
  __builtin_amdgcn_global_load_lds(
      (const __attribute__((address_space(1))) unsigned int*)g,
      (__attribute__((address_space(3))) unsigned int*)l,
      16, 0, 0);
}

// ======== k_front: gate/acts0 + W1T/cv (everything GEMM1 depends on) ========
// blocks   0..255 : gate/acts0: 8 rows/block (halves We0 wave-replication:
//                   201->100MB), 4 waves split d into 192-chunks, LDS partial
//                   reduce; finalize/fixup = R1's verified 2-rows-per-wave code.
// blocks 256..639 : expert j transpose We1[j]->W1T, dbk seg-split 3x;
//                   cv partials to cvp[seg] (summed in GEMM1 preload)
// (B2T build lives in GEMM1's launch as rider blocks.)
__global__ __launch_bounds__(256) void k_front(const float* __restrict__ x,
                                               const float* __restrict__ We0,
                                               const float* __restrict__ be0,
                                               const float* __restrict__ bd0,
                                               const float* __restrict__ We1,
                                               const float* __restrict__ bd1,
                                               const float* __restrict__ be1,
                                               u16* __restrict__ W1T,
                                               float* __restrict__ cvp,
                                               u16* __restrict__ xb,
                                               u16* __restrict__ A2) {
  __shared__ float smem[10760];                 // 43 KB, shared by branches
  const int bid = blockIdx.x, t = threadIdx.x;
  if (bid < 256) {
    // ---------------- gate branch: rows b0..b0+7 ----------------
    const int b0 = bid * 8;
    float* xs   = smem;                         // [8][768] = x - bd0
    float* part = smem + 6144;                  // [4 waves][8 rows][128]
    float* wqp  = smem + 10240;                 // [4 waves][128] ||We0||^2 partials
    float* xns  = smem + 10752;                 // [8] row norms
#pragma unroll
    for (int i = 0; i < 6; ++i) {
      int idx = t + i * 256;                    // 1536 float4
      int r = idx / 192, c4 = idx % 192;
      size_t go = (size_t)(b0 + r) * DDATA + c4 * 4;
      float4 v = *(const float4*)&x[go];
      ushort4 o;
      o.x = f2bf(v.x); o.y = f2bf(v.y); o.z = f2bf(v.z); o.w = f2bf(v.w);
      *(ushort4*)&xb[go] = o;                   // fused x cast for GEMM1
      float4 b4 = *(const float4*)&bd0[c4 * 4];
      v.x -= b4.x; v.y -= b4.y; v.z -= b4.z; v.w -= b4.w;
      *(float4*)&xs[r * DDATA + c4 * 4] = v;
    }
    __syncthreads();
    const int ln = t & 63, w = t >> 6;
    // row norms: wave w owns rows 2w, 2w+1
#pragma unroll
    for (int rr = 0; rr < 2; ++rr) {
      int r = w * 2 + rr;
      float a = 0.f;
#pragma unroll
      for (int q = 0; q < 12; ++q) { float xv = xs[r * DDATA + ln + q * 64]; a += xv * xv; }
#pragma unroll
      for (int sh = 32; sh; sh >>= 1) a += __shfl_xor(a, sh, 64);
      if (ln == 0) xns[r] = a;
    }
    const int j0 = ln * 2;                      // 2 experts per lane
    // wave w accumulates d in [w*192, w*192+192) for ALL 8 rows (partials)
    float a0[8], a1[8];
    float wq0 = 0.f, wq1 = 0.f;
#pragma unroll
    for (int r = 0; r < 8; ++r) { a0[r] = 0.f; a1[r] = 0.f; }
    const int dbase = w * 192;
    for (int d = dbase; d < dbase + 192; d += 4) {
      float4 xv[8];
#pragma unroll
      for (int r = 0; r < 8; ++r) xv[r] = *(const float4*)&xs[r * DDATA + d];
#pragma unroll
      for (int dd = 0; dd < 4; ++dd) {
        float2 w2 = *(const float2*)&We0[(size_t)(d + dd) * 128 + j0];
#pragma unroll
        for (int r = 0; r < 8; ++r) {
          float xr = ((const float*)&xv[r])[dd];
          a0[r] += xr * w2.x; a1[r] += xr * w2.y;
        }
        wq0 += w2.x * w2.x; wq1 += w2.y * w2.y;
      }
    }
#pragma unroll
    for (int r = 0; r < 8; ++r)
      *(float2*)&part[(w * 8 + r) * 128 + j0] = make_float2(a0[r], a1[r]);
    *(float2*)&wqp[w * 128 + j0] = make_float2(wq0, wq1);
    __syncthreads();
    // finalize: wave w owns rows 2w, 2w+1 (R1-verified structure)
    float pa0 = be0[j0], pa1 = be0[j0 + 1];
    float pb0 = pa0, pb1 = pa1;
    float wn0 = 0.f, wn1 = 0.f;
#pragma unroll
    for (int q = 0; q < 4; ++q) {
      float2 prA = *(const float2*)&part[(q * 8 + 2 * w) * 128 + j0];
      float2 prB = *(const float2*)&part[(q * 8 + 2 * w + 1) * 128 + j0];
      pa0 += prA.x; pa1 += prA.y;
      pb0 += prB.x; pb1 += prB.y;
      float2 wr2 = *(const float2*)&wqp[q * 128 + j0];
      wn0 += wr2.x; wn1 += wr2.y;
    }
    const float sA = sqrtf(xns[2 * w]), sB = sqrtf(xns[2 * w + 1]);
    const float w0 = sqrtf(wn0), w1 = sqrtf(wn1);
    const size_t rowA = (size_t)(b0 + 2 * w) * KA2;
    const size_t rowB = rowA + KA2;
    unsigned pka = (unsigned)f2bf(pa0 > 0.f ? pa0 : 0.f) |
                   ((unsigned)f2bf(pa1 > 0.f ? pa1 : 0.f) << 16);
    unsigned gka = (pa0 > 0.f ? 0x3F80u : 0u) | (pa1 > 0.f ? 0x3F800000u : 0u);
    unsigned pkb = (unsigned)f2bf(pb0 > 0.f ? pb0 : 0.f) |
                   ((unsigned)f2bf(pb1 > 0.f ? pb1 : 0.f) << 16);
    unsigned gkb = (pb0 > 0.f ? 0x3F80u : 0u) | (pb1 > 0.f ? 0x3F800000u : 0u);
    *(unsigned*)&A2[rowA + NJK + j0]       = pka;
    *(unsigned*)&A2[rowA + NJK + 128 + j0] = gka;
    *(unsigned*)&A2[rowB + NJK + j0]       = pkb;
    *(unsigned*)&A2[rowB + NJK + 128 + j0] = gkb;
    // fp32 sign uncertain -> whole wave cooperates on exact fp64 recompute
    const float tA0 = 1e-4f * sA * w0, tA1 = 1e-4f * sA * w1;
    const float tB0 = 1e-4f * sB * w0, tB1 = 1e-4f * sB * w1;
#pragma unroll
    for (int c = 0; c < 4; ++c) {
      float pv = c == 0 ? pa0 : c == 1 ? pa1 : c == 2 ? pb0 : pb1;
      float tv = c == 0 ? tA0 : c == 1 ? tA1 : c == 2 ? tB0 : tB1;
      unsigned long long mask = __ballot(fabsf(pv) <= tv);
      const int bb = b0 + 2 * w + (c >> 1);
      while (mask) {
        int src = (int)__builtin_ctzll(mask);
        mask &= mask - 1;
        int jj = src * 2 + (c & 1);
        double acc = 0.0;
#pragma unroll
        for (int q = 0; q < 12; ++q) {
          int d = ln + q * 64;
          acc += (double)(x[(size_t)bb * DDATA + d] - bd0[d]) *
                 (double)We0[(size_t)d * 128 + jj];
        }
#pragma unroll
        for (int sh = 32; sh; sh >>= 1) acc += __shfl_xor(acc, sh, 64);
        if (ln == src) {
          double pd = acc + (double)be0[jj];
          size_t rw = (size_t)bb * KA2;
          A2[rw + NJK + jj]       = f2bf(pd > 0.0 ? (float)pd : 0.f);
          A2[rw + NJK + 128 + jj] = (pd > 0.0) ? (u16)0x3F80 : (u16)0;
        }
      }
    }
  } else {
    // ---------------- We1 transpose + cv partials (j, seg) ----------------
    const int e = bid - 256;
    const int j = e & 127, seg = e >> 7;        // seg 0..2 -> dbk seg*4..seg*4+3
    float* ts  = smem;                          // 64*33
    float* bds = smem + 64 * 33;                // 64
    float* red = smem + 64 * 33 + 64;           // 8*32
    const int k = t & 31, g = t >> 5;
    float cacc = 0.f;
    for (int db = seg * 4; db < seg * 4 + 4; ++db) {
      const float* src = We1 + (size_t)j * 24576 + db * 2048;  // 64 d x 32 k
#pragma unroll
      for (int i = 0; i < 8; ++i) {
        int ee = t + i * 256;
        ts[(ee >> 5) * 33 + (ee & 31)] = src[ee];
      }
      if (t < 64) bds[t] = bd1[(size_t)j * DDATA + db * 64 + t];
      __syncthreads();
#pragma unroll
      for (int i = 0; i < 8; ++i) {
        int ee = t + i * 256;
        int kk = ee >> 6, d = ee & 63;
        W1T[(size_t)(j * 32 + kk) * DDATA + db * 64 + d] = f2bf(ts[d * 33 + kk]);
      }
#pragma unroll
      for (int q = 0; q < 8; ++q) {
        int d = g + 8 * q;
        cacc += ts[d * 33 + k] * bds[d];
      }
      __syncthreads();
    }
    red[g * 32 + k] = cacc;
    __syncthreads();
    if (g == 0) {
      float s = 0.f;
#pragma unroll
      for (int q = 0; q < 8; ++q) s += red[q * 32 + k];
      cvp[seg * 4096 + j * 32 + k] = (seg == 0 ? be1[j * 32 + k] : 0.f) - s;
    }
  }
}

// ------ GEMM: C = A[M,K] * B^T[N,K], bf16 MFMA 16x16x32, XOR-swizzled LDS ------
// Single-buffer 2-phase loop, __syncthreads only (proven-correct sync).
// BK is a template param: per-round data shows per-K-step cost ~constant
// regardless of bytes -> fewer/bigger steps (G1: BK=128, 12->6 steps) should
// nearly halve the latency-serial term. Swizzle generalizes (XOR low 3 bits
// of the 16B-chunk index; bijective within each 8-chunk group).
// EPI=1 carries B2TB rider blocks (h < B2TB) building B2T during stalls.
// XCD-chunked 1-D grid: blocks sharing B-panels land on ONE XCD (T1).
template<int BM, int BN, int EPI, int BK>
__global__ __launch_bounds__(256) void k_gemm(const u16* __restrict__ A,
                                              const u16* __restrict__ Bm,
                                              int K, int Kc,
                                              float* __restrict__ outF,
                                              u16* __restrict__ A2,
                                              const float* __restrict__ cvec,
                                              const float* __restrict__ Wd1,
                                              const float* __restrict__ Wd0,
                                              const float* __restrict__ bd1,
                                              u16* __restrict__ B2Tp) {
  constexpr int WM = BM / 32, WN = BN / 32;
  constexpr int CPR = BK / 8;                   // 16B chunks per LDS row
  __shared__ __align__(16) u16 AsBs[(BM + BN) * BK];   // As | Bs
  __shared__ u16 gate_s[BM * 4];
  __shared__ float cv_s[BN];
  const int tid = threadIdx.x;
  const int h = blockIdx.x;

  if (EPI == 1 && h < B2TB) {
    // ------- B2T rider: [W_dec1 ; W_dec0 ; b_dec1]^T, 68 rb x 12 dbk -------
    float* fsm = (float*)&AsBs[0];              // >= 64*65*4 = 16.9KB
    const int rb = h / 12, dbk = h % 12;
    const float* src; int r0, base;
    if (rb < 64)      { src = Wd1; r0 = rb * 64;        base = 0;    }
    else if (rb < 66) { src = Wd0; r0 = (rb - 64) * 64; base = 4096; }
    else              { src = bd1; r0 = (rb - 66) * 64; base = 4224; }
    const int d0 = dbk * 64;
#pragma unroll
    for (int i = 0; i < 16; ++i) {
      int ee = tid + i * 256;
      int ri = ee >> 6, di = ee & 63;
      fsm[ri * 65 + di] = src[(size_t)(r0 + ri) * DDATA + d0 + di];
    }
    __syncthreads();
#pragma unroll
    for (int i = 0; i < 16; ++i) {
      int ee = tid + i * 256;
      int di = ee >> 6, ri = ee & 63;
      B2Tp[(size_t)(d0 + di) * KA2 + base + r0 + ri] = f2bf(fsm[ri * 65 + di]);
    }
    return;
  }

  int bx, by, bz;
  if (EPI == 1) {
    // gemm blocks: hg = h - B2TB in [0,1024); B2TB%8==0 keeps XCD = h%8
    const int hg = h - B2TB;
    const int l = (hg & 7) * 128 + (hg >> 3);   // bijective: 1024 = 8*128
    const int g2 = l >> 7, w = l & 127;         // chunk on XCD
    by = w >> 2; bx = (g2 << 2) + (w & 3); bz = 0;
  } else {
    const int l = (h & 7) * 96 + (h >> 3);      // bijective: 768 = 8*96
    bx = l >> 7; const int r2 = l & 127; bz = r2 >> 5; by = r2 & 31;
  }
  const int kbase = bz * Kc;
  const u16* Ab = A  + (size_t)(by * BM) * K;
  const u16* Bb = Bm + (size_t)(bx * BN) * K;
  const int wave = tid >> 6, lane = tid & 63;
  const int wr = wave >> 1, wc = wave & 1;
  const int m0 = wr * (BM / 2), n0 = wc * (BN / 2);
  const int lm = lane & 15, qd = lane >> 4;
  u16* As = &AsBs[0];
  u16* Bs = &AsBs[BM * BK];

  if (EPI == 1) {
    // preload epilogue data up front (ready; in-loop barriers cover the sync)
    for (int e = tid; e < BM * 4; e += 256) {
      int r = e >> 2, q = e & 3;
      gate_s[e] = A2[(size_t)(by * BM + r) * KA2 + NJK + 128 + bx * 4 + q];
    }
    for (int e = tid; e < BN; e += 256)
      cv_s[e] = cvec[bx * BN + e] + cvec[4096 + bx * BN + e] + cvec[8192 + bx * BN + e];
  }

  f32x4 acc[WM][WN];
  const f32x4 zero = {0.f, 0.f, 0.f, 0.f};
  for (int mi = 0; mi < WM; ++mi)
    for (int ni = 0; ni < WN; ++ni) acc[mi][ni] = zero;

  for (int k0 = kbase; k0 < kbase + Kc; k0 += BK) {
#pragma unroll
    for (int i = 0; i < BM * BK / 2048; ++i) {
      int id = tid + 256 * i;
      int row = id / CPR, u = id % CPR;
      gload16(Ab + (size_t)row * K + k0 + ((u ^ (row & 7)) * 8), &As[id * 8]);
    }
#pragma unroll
    for (int i = 0; i < BN * BK / 2048; ++i) {
      int id = tid + 256 * i;
      int row = id / CPR, u = id % CPR;
      gload16(Bb + (size_t)row * K + k0 + ((u ^ (row & 7)) * 8), &Bs[id * 8]);
    }
    __syncthreads();
#pragma unroll
    for (int s = 0; s < BK / 32; ++s) {
      const int swz = ((s << 2) + qd) ^ (lm & 7);
      bf16x8 af[WM], bfv[WN];
#pragma unroll
      for (int mi = 0; mi < WM; ++mi)
        af[mi] = *(const bf16x8*)&As[(m0 + mi * 16 + lm) * BK + swz * 8];
#pragma unroll
      for (int ni = 0; ni < WN; ++ni)
        bfv[ni] = *(const bf16x8*)&Bs[(n0 + ni * 16 + lm) * BK + swz * 8];
#pragma unroll
      for (int mi = 0; mi < WM; ++mi)
#pragma unroll
        for (int ni = 0; ni < WN; ++ni)
          acc[mi][ni] = __builtin_amdgcn_mfma_f32_16x16x32_bf16(af[mi], bfv[ni],
                                                                acc[mi][ni], 0, 0, 0);
    }
    __syncthreads();
  }

  const int rb = qd * 4;
#pragma unroll
  for (int mi = 0; mi < WM; ++mi) {
#pragma unroll
    for (int ni = 0; ni < WN; ++ni) {
#pragma unroll
      for (int r = 0; r < 4; ++r) {
        int ml = m0 + mi * 16 + rb + r;
        int nl = n0 + ni * 16 + lm;
        int gm = by * BM + ml;
        int gn = bx * BN + nl;
        float v = acc[mi][ni][r];
        if (EPI == 1) {
          v += cv_s[nl];
          v = v > 0.f ? v : 0.f;
          u16 gbit = gate_s[ml * 4 + (nl >> 5)];
          v = gbit ? v : 0.f;
          float vn = __shfl_xor(v, 1, 64);        // pack even/odd columns
          if ((lm & 1) == 0) {
            unsigned pk = (unsigned)f2bf(v) | ((unsigned)f2bf(vn) << 16);
            *(unsigned*)&A2[(size_t)gm * KA2 + gn] = pk;
          }
        } else {
          outF[((size_t)bz * B_SZ + gm) * DDATA + gn] = v;
        }
      }
    }
  }
}

// ---------------- reduce split-K partials + bias ----------------
__global__ __launch_bounds__(256) void k_reduce(const float* __restrict__ part,
                                                const float* __restrict__ bias,
                                                float* __restrict__ out) {
  const int N4 = B_SZ * DDATA / 4;
  int i = blockIdx.x * 256 + threadIdx.x;
  const float4* p4 = (const float4*)part;
  float4 s = p4[i];
#pragma unroll
  for (int z = 1; z < SPLITK; ++z) {
    float4 t = p4[i + z * N4];
    s.x += t.x; s.y += t.y; s.z += t.z; s.w += t.w;
  }
  float4 b = ((const float4*)bias)[i % (DDATA / 4)];
  s.x += b.x; s.y += b.y; s.z += b.z; s.w += b.w;
  ((float4*)out)[i] = s;
}

extern "C" void kernel_launch(void* const* d_in, const int* in_sizes, int n_in,
                              void* d_out, int out_size, void* d_ws, size_t ws_size,
                              hipStream_t stream) {
  const float* x   = (const float*)d_in[0];
  const float* We0 = (const float*)d_in[1];
  const float* be0 = (const float*)d_in[2];
  const float* Wd0 = (const float*)d_in[3];
  const float* bd0 = (const float*)d_in[4];
  const float* We1 = (const float*)d_in[5];
  const float* be1 = (const float*)d_in[6];
  const float* Wd1 = (const float*)d_in[7];
  const float* bd1 = (const float*)d_in[8];
  float* out = (float*)d_out;

  uint8_t* ws = (uint8_t*)d_ws;
  size_t off = 0;
  auto carve = [&](size_t bytes) {
    uint8_t* p = ws + off;
    off += (bytes + 255) & ~(size_t)255;
    return p;
  };
  u16*    A2   = (u16*)carve((size_t)B_SZ * KA2 * 2);
  u16*    xb   = (u16*)carve((size_t)B_SZ * DDATA * 2);
  u16*    W1T  = (u16*)carve((size_t)NJK * DDATA * 2);
  u16*    B2T  = (u16*)carve((size_t)DDATA * KA2 * 2);
  float*  cvp  = (float*)carve((size_t)3 * NJK * 4);
  float*  part = (float*)carve((size_t)SPLITK * B_SZ * DDATA * 4);   // 25.2 MB

  // gate+acts0+fixup (8 rows/block), W1T/cv (GEMM1's deps only)
  k_front <<<640, 256, 0, stream>>>(x, We0, be0, bd0, We1, bd1, be1,
                                    W1T, cvp, xb, A2);
  // GEMM1 (M=2048,N=4096,K=768): 64x128 tile, BK=128 -> 6 K-steps,
  // 1024 gemm blocks (3/CU, LDS 50KB) + 816 B2T riders dispatched first
  k_gemm<64, 128, 1, 128><<<B2TB + 1024, 256, 0, stream>>>(
      xb, W1T, DDATA, DDATA, nullptr, A2, cvp, Wd1, Wd0, bd1, B2T);
  // GEMM2 split-K (M=2048,N=768,K=4352): 64x128 tile, BK=64, 768 blocks (3/CU)
  k_gemm<64, 128, 2, 64><<<768, 256, 0, stream>>>(
      A2, B2T, KA2, KC2, part, nullptr, nullptr, nullptr, nullptr, nullptr, nullptr);
  k_reduce<<<1536, 256, 0, stream>>>(part, bd0, out);
}

// Round 9
// 160.719 us; speedup vs baseline: 1.6030x; 1.0188x over previous
//
#include <hip/hip_runtime.h>
#include <hip/hip_bf16.h>
#include <stdint.h>

#define B_SZ   2048
#define DDATA  768
#define NSAE   128
#define NJK    4096   // NSAE*32
#define KA2    4352   // NJK + 128 (acts0) + 128 (gate)
#define SPLITK 4
#define KC2    1088   // KA2 / SPLITK (17 x BK=64)

typedef unsigned short u16;
typedef short bf16x8 __attribute__((ext_vector_type(8)));
typedef float f32x4  __attribute__((ext_vector_type(4)));

static __device__ __forceinline__ u16 f2bf(float f) {
  __hip_bfloat16 h = __float2bfloat16(f);
  return *reinterpret_cast<u16*>(&h);
}

static __device__ __forceinline__ void gload16(const u16* g, u16* l) {
  __builtin_amdgcn_global_load_lds(
      (const __attribute__((address_space(1))) unsigned int*)g,
      (__attribute__((address_space(3))) unsigned int*)l,
      16, 0, 0);
}

// ======== k_front: ALL pre-GEMM work in ONE kernel (R3-verified layout) ========
// blocks    0..511 : gate/acts0: 4 rows/block, 4 waves split d into 192-chunks
// blocks  512..895 : expert j transpose We1[j]->W1T, dbk seg-split 3x;
//                    cv partials to cvp[seg] (summed in GEMM1 preload)
// blocks 896..1711 : B2T build ([W_dec1 ; W_dec0 ; b_dec1]^T), 68 rb x 12 dbk
__global__ __launch_bounds__(256) void k_front(const float* __restrict__ x,
                                               const float* __restrict__ We0,
                                               const float* __restrict__ be0,
                                               const float* __restrict__ bd0,
                                               const float* __restrict__ We1,
                                               const float* __restrict__ bd1,
                                               const float* __restrict__ be1,
                                               const float* __restrict__ Wd1,
                                               const float* __restrict__ Wd0,
                                               u16* __restrict__ W1T,
                                               float* __restrict__ cvp,
                                               u16* __restrict__ B2T,
                                               u16* __restrict__ xb,
                                               u16* __restrict__ A2) {
  __shared__ float smem[6280];                  // 25.1 KB, shared by all branches
  const int bid = blockIdx.x, t = threadIdx.x;
  if (bid < 512) {
    // ---------------- gate branch: rows b0..b0+3 ----------------
    const int b0 = bid * 4;
    float* xs   = smem;                         // [4][768] = x - bd0
    float* part = smem + 3072;                  // [4 waves][4 rows][128]
    float* wqp  = smem + 5120;                  // [4 waves][128] ||We0||^2 partials
    float* xns  = smem + 5632;                  // [4] row norms
#pragma unroll
    for (int i = 0; i < 3; ++i) {
      int idx = t + i * 256;                    // 768 float4
      int r = idx / 192, c4 = idx % 192;
      size_t go = (size_t)(b0 + r) * DDATA + c4 * 4;
      float4 v = *(const float4*)&x[go];
      ushort4 o;
      o.x = f2bf(v.x); o.y = f2bf(v.y); o.z = f2bf(v.z); o.w = f2bf(v.w);
      *(ushort4*)&xb[go] = o;                   // fused x cast for GEMM1
      float4 b4 = *(const float4*)&bd0[c4 * 4];
      v.x -= b4.x; v.y -= b4.y; v.z -= b4.z; v.w -= b4.w;
      *(float4*)&xs[r * DDATA + c4 * 4] = v;
    }
    __syncthreads();
    const int ln = t & 63, w = t >> 6;
    {                                           // row norm: wave w owns row w
      float a = 0.f;
#pragma unroll
      for (int q = 0; q < 12; ++q) { float xv = xs[w * DDATA + ln + q * 64]; a += xv * xv; }
#pragma unroll
      for (int sh = 32; sh; sh >>= 1) a += __shfl_xor(a, sh, 64);
      if (ln == 0) xns[w] = a;
    }
    const int j0 = ln * 2;                      // 2 experts per lane
    // wave w accumulates d in [w*192, w*192+192) for ALL 4 rows (partials)
    float a00=0.f,a01=0.f,a10=0.f,a11=0.f,a20=0.f,a21=0.f,a30=0.f,a31=0.f;
    float wq0=0.f, wq1=0.f;
    const int dbase = w * 192;
    for (int d = dbase; d < dbase + 192; d += 4) {
      float4 xv0 = *(const float4*)&xs[0 * DDATA + d];   // wave-uniform bcast
      float4 xv1 = *(const float4*)&xs[1 * DDATA + d];
      float4 xv2 = *(const float4*)&xs[2 * DDATA + d];
      float4 xv3 = *(const float4*)&xs[3 * DDATA + d];
#pragma unroll
      for (int dd = 0; dd < 4; ++dd) {
        float2 w2 = *(const float2*)&We0[(size_t)(d + dd) * 128 + j0];
        float x0 = ((const float*)&xv0)[dd], x1 = ((const float*)&xv1)[dd];
        float x2 = ((const float*)&xv2)[dd], x3 = ((const float*)&xv3)[dd];
        a00 += x0 * w2.x; a01 += x0 * w2.y;
        a10 += x1 * w2.x; a11 += x1 * w2.y;
        a20 += x2 * w2.x; a21 += x2 * w2.y;
        a30 += x3 * w2.x; a31 += x3 * w2.y;
        wq0 += w2.x * w2.x; wq1 += w2.y * w2.y;
      }
    }
    *(float2*)&part[(w * 4 + 0) * 128 + j0] = make_float2(a00, a01);
    *(float2*)&part[(w * 4 + 1) * 128 + j0] = make_float2(a10, a11);
    *(float2*)&part[(w * 4 + 2) * 128 + j0] = make_float2(a20, a21);
    *(float2*)&part[(w * 4 + 3) * 128 + j0] = make_float2(a30, a31);
    *(float2*)&wqp[w * 128 + j0] = make_float2(wq0, wq1);
    __syncthreads();
    // finalize: wave w owns row w; lane handles experts j0, j0+1
    float p0 = be0[j0], p1 = be0[j0 + 1];
    float wn0 = 0.f, wn1 = 0.f;
#pragma unroll
    for (int q = 0; q < 4; ++q) {
      float2 pr = *(const float2*)&part[(q * 4 + w) * 128 + j0];
      p0 += pr.x; p1 += pr.y;
      float2 wr2 = *(const float2*)&wqp[q * 128 + j0];
      wn0 += wr2.x; wn1 += wr2.y;
    }
    const float sx = sqrtf(xns[w]);
    const float tau0 = 1e-4f * sx * sqrtf(wn0);
    const float tau1 = 1e-4f * sx * sqrtf(wn1);
    const int bb = b0 + w;
    const size_t row = (size_t)bb * KA2;
    unsigned pk = (unsigned)f2bf(p0 > 0.f ? p0 : 0.f) |
                  ((unsigned)f2bf(p1 > 0.f ? p1 : 0.f) << 16);
    unsigned gk = (p0 > 0.f ? 0x3F80u : 0u) | (p1 > 0.f ? 0x3F800000u : 0u);
    *(unsigned*)&A2[row + NJK + j0]       = pk;
    *(unsigned*)&A2[row + NJK + 128 + j0] = gk;
    // fp32 sign uncertain -> whole wave cooperates on exact fp64 recompute
#pragma unroll
    for (int c = 0; c < 2; ++c) {
      float pv = c ? p1 : p0;
      float tv = c ? tau1 : tau0;
      unsigned long long mask = __ballot(fabsf(pv) <= tv);
      while (mask) {
        int src = (int)__builtin_ctzll(mask);
        mask &= mask - 1;
        int jj = src * 2 + c;
        double acc = 0.0;
#pragma unroll
        for (int q = 0; q < 12; ++q) {
          int d = ln + q * 64;
          acc += (double)(x[(size_t)bb * DDATA + d] - bd0[d]) *
                 (double)We0[(size_t)d * 128 + jj];
        }
#pragma unroll
        for (int sh = 32; sh; sh >>= 1) acc += __shfl_xor(acc, sh, 64);
        if (ln == src) {
          double pd = acc + (double)be0[jj];
          A2[row + NJK + jj]       = f2bf(pd > 0.0 ? (float)pd : 0.f);
          A2[row + NJK + 128 + jj] = (pd > 0.0) ? (u16)0x3F80 : (u16)0;
        }
      }
    }
  } else if (bid < 896) {
    // ---------------- We1 transpose + cv partials (j, seg) ----------------
    const int e = bid - 512;
    const int j = e & 127, seg = e >> 7;        // seg 0..2 -> dbk seg*4..seg*4+3
    float* ts  = smem;                          // 64*33
    float* bds = smem + 64 * 33;                // 64
    float* red = smem + 64 * 33 + 64;           // 8*32
    const int k = t & 31, g = t >> 5;
    float cacc = 0.f;
    for (int db = seg * 4; db < seg * 4 + 4; ++db) {
      const float* src = We1 + (size_t)j * 24576 + db * 2048;  // 64 d x 32 k
#pragma unroll
      for (int i = 0; i < 8; ++i) {
        int ee = t + i * 256;
        ts[(ee >> 5) * 33 + (ee & 31)] = src[ee];
      }
      if (t < 64) bds[t] = bd1[(size_t)j * DDATA + db * 64 + t];
      __syncthreads();
#pragma unroll
      for (int i = 0; i < 8; ++i) {
        int ee = t + i * 256;
        int kk = ee >> 6, d = ee & 63;
        W1T[(size_t)(j * 32 + kk) * DDATA + db * 64 + d] = f2bf(ts[d * 33 + kk]);
      }
#pragma unroll
      for (int q = 0; q < 8; ++q) {
        int d = g + 8 * q;
        cacc += ts[d * 33 + k] * bds[d];
      }
      __syncthreads();
    }
    red[g * 32 + k] = cacc;
    __syncthreads();
    if (g == 0) {
      float s = 0.f;
#pragma unroll
      for (int q = 0; q < 8; ++q) s += red[q * 32 + k];
      cvp[seg * 4096 + j * 32 + k] = (seg == 0 ? be1[j * 32 + k] : 0.f) - s;
    }
  } else {
    // ---------------- B2T build ----------------
    const int e2 = bid - 896;
    const int rb = e2 / 12, dbk = e2 % 12;
    const float* src; int r0, base;
    if (rb < 64)      { src = Wd1; r0 = rb * 64;        base = 0;    }
    else if (rb < 66) { src = Wd0; r0 = (rb - 64) * 64; base = 4096; }
    else              { src = bd1; r0 = (rb - 66) * 64; base = 4224; }
    const int d0 = dbk * 64;
#pragma unroll
    for (int i = 0; i < 16; ++i) {
      int ee = t + i * 256;
      int ri = ee >> 6, di = ee & 63;
      smem[ri * 65 + di] = src[(size_t)(r0 + ri) * DDATA + d0 + di];
    }
    __syncthreads();
#pragma unroll
    for (int i = 0; i < 16; ++i) {
      int ee = t + i * 256;
      int di = ee >> 6, ri = ee & 63;
      B2T[(size_t)(d0 + di) * KA2 + base + r0 + ri] = f2bf(smem[ri * 65 + di]);
    }
  }
}

// ------ GEMM: C = A[M,K] * B^T[N,K], bf16 MFMA 16x16x32, BK=64, XOR-swizzled LDS ------
// PROPER 2-phase double-buffer (T3 minimum recipe, first time actually run):
//   stage(t+1, buf^1) issued BEFORE compute(t, buf); ONE __syncthreads per
//   K-step. The barrier's implicit vmcnt(0) drain lands AFTER compute has
//   covered the staging latency -- unlike all prior rounds' drain-first or
//   two-barrier loops. __syncthreads only (compiler-fenced; no R5 race class).
// XCD-chunked 1-D grid: blocks sharing B-panels land on ONE XCD (T1).
// EPI=1: v = relu(v + c[gn]) * gate -> bf16x2 A2 ;  EPI=2: split-K fp32 partials
template<int BM, int BN, int EPI>
__global__ __launch_bounds__(256) void k_gemm(const u16* __restrict__ A,
                                              const u16* __restrict__ Bm,
                                              int K, int Kc,
                                              float* __restrict__ outF,
                                              u16* __restrict__ A2,
                                              const float* __restrict__ cvec) {
  constexpr int WM = BM / 32, WN = BN / 32;
  __shared__ __align__(16) u16 As[2][BM * 64];
  __shared__ __align__(16) u16 Bs[2][BN * 64];
  __shared__ u16 gate_s[BM * 4];
  __shared__ float cv_s[BN];
  const int tid = threadIdx.x;
  int bx, by, bz;
  {
    const int h = blockIdx.x;
    if (EPI == 1) {
      // grid 1024 = 8 XCD-chunks of 128 (by 0..31 x 4 bx) -> L2-local panels
      const int l = (h & 7) * 128 + (h >> 3);   // bijective: 1024 = 8*128
      const int g2 = l >> 7, w = l & 127;       // chunk g2 on XCD (h&7)
      by = w >> 2; bx = (g2 << 2) + (w & 3); bz = 0;
    } else {
      const int l = (h & 7) * 96 + (h >> 3);    // bijective: 768 = 8*96
      bx = l >> 7; const int r2 = l & 127; bz = r2 >> 5; by = r2 & 31;
    }
  }
  const int kbase = bz * Kc;
  const u16* Ab = A  + (size_t)(by * BM) * K;
  const u16* Bb = Bm + (size_t)(bx * BN) * K;
  const int wave = tid >> 6, lane = tid & 63;
  const int wr = wave >> 1, wc = wave & 1;
  const int m0 = wr * (BM / 2), n0 = wc * (BN / 2);
  const int lm = lane & 15, qd = lane >> 4;

  if (EPI == 1) {
    // preload epilogue data up front (in-loop barriers cover the sync)
    for (int e = tid; e < BM * 4; e += 256) {
      int r = e >> 2, q = e & 3;
      gate_s[e] = A2[(size_t)(by * BM + r) * KA2 + NJK + 128 + bx * 4 + q];
    }
    for (int e = tid; e < BN; e += 256)
      cv_s[e] = cvec[bx * BN + e] + cvec[4096 + bx * BN + e] + cvec[8192 + bx * BN + e];
  }

  f32x4 acc[WM][WN];
  const f32x4 zero = {0.f, 0.f, 0.f, 0.f};
  for (int mi = 0; mi < WM; ++mi)
    for (int ni = 0; ni < WN; ++ni) acc[mi][ni] = zero;

  auto stage = [&](int kt, int buf) {
    const int k0 = kbase + kt * 64;
#pragma unroll
    for (int i = 0; i < BM / 32; ++i) {
      int id = tid + 256 * i;
      int row = id >> 3, u = id & 7;
      gload16(Ab + (size_t)row * K + k0 + ((u ^ (row & 7)) * 8), &As[buf][id * 8]);
    }
#pragma unroll
    for (int i = 0; i < BN / 32; ++i) {
      int id = tid + 256 * i;
      int row = id >> 3, u = id & 7;
      gload16(Bb + (size_t)row * K + k0 + ((u ^ (row & 7)) * 8), &Bs[buf][id * 8]);
    }
  };
  auto compute = [&](int buf) {
#pragma unroll
    for (int s = 0; s < 2; ++s) {
      const int swz = ((s << 2) + qd) ^ (lm & 7);
      bf16x8 af[WM], bfv[WN];
#pragma unroll
      for (int mi = 0; mi < WM; ++mi)
        af[mi] = *(const bf16x8*)&As[buf][(m0 + mi * 16 + lm) * 64 + swz * 8];
#pragma unroll
      for (int ni = 0; ni < WN; ++ni)
        bfv[ni] = *(const bf16x8*)&Bs[buf][(n0 + ni * 16 + lm) * 64 + swz * 8];
#pragma unroll
      for (int mi = 0; mi < WM; ++mi)
#pragma unroll
        for (int ni = 0; ni < WN; ++ni)
          acc[mi][ni] = __builtin_amdgcn_mfma_f32_16x16x32_bf16(af[mi], bfv[ni],
                                                                acc[mi][ni], 0, 0, 0);
    }
  };

  const int NT = Kc / 64;
  stage(0, 0);
  __syncthreads();                              // buf0 ready
  int cur = 0;
  for (int t = 0; t < NT; ++t) {
    if (t + 1 < NT) stage(t + 1, cur ^ 1);      // issue BEFORE compute
    compute(cur);                               // staging latency hides here
    __syncthreads();                            // one barrier per step:
    cur ^= 1;                                   // drains stage(t+1) + reads done
  }

  const int rb = qd * 4;
#pragma unroll
  for (int mi = 0; mi < WM; ++mi) {
#pragma unroll
    for (int ni = 0; ni < WN; ++ni) {
#pragma unroll
      for (int r = 0; r < 4; ++r) {
        int ml = m0 + mi * 16 + rb + r;
        int nl = n0 + ni * 16 + lm;
        int gm = by * BM + ml;
        int gn = bx * BN + nl;
        float v = acc[mi][ni][r];
        if (EPI == 1) {
          v += cv_s[nl];
          v = v > 0.f ? v : 0.f;
          u16 gbit = gate_s[ml * 4 + (nl >> 5)];
          v = gbit ? v : 0.f;
          float vn = __shfl_xor(v, 1, 64);        // pack even/odd columns
          if ((lm & 1) == 0) {
            unsigned pk = (unsigned)f2bf(v) | ((unsigned)f2bf(vn) << 16);
            *(unsigned*)&A2[(size_t)gm * KA2 + gn] = pk;
          }
        } else {
          outF[((size_t)bz * B_SZ + gm) * DDATA + gn] = v;
        }
      }
    }
  }
}

// ---------------- reduce split-K partials + bias ----------------
__global__ __launch_bounds__(256) void k_reduce(const float* __restrict__ part,
                                                const float* __restrict__ bias,
                                                float* __restrict__ out) {
  const int N4 = B_SZ * DDATA / 4;
  int i = blockIdx.x * 256 + threadIdx.x;
  const float4* p4 = (const float4*)part;
  float4 s = p4[i];
#pragma unroll
  for (int z = 1; z < SPLITK; ++z) {
    float4 t = p4[i + z * N4];
    s.x += t.x; s.y += t.y; s.z += t.z; s.w += t.w;
  }
  float4 b = ((const float4*)bias)[i % (DDATA / 4)];
  s.x += b.x; s.y += b.y; s.z += b.z; s.w += b.w;
  ((float4*)out)[i] = s;
}

extern "C" void kernel_launch(void* const* d_in, const int* in_sizes, int n_in,
                              void* d_out, int out_size, void* d_ws, size_t ws_size,
                              hipStream_t stream) {
  const float* x   = (const float*)d_in[0];
  const float* We0 = (const float*)d_in[1];
  const float* be0 = (const float*)d_in[2];
  const float* Wd0 = (const float*)d_in[3];
  const float* bd0 = (const float*)d_in[4];
  const float* We1 = (const float*)d_in[5];
  const float* be1 = (const float*)d_in[6];
  const float* Wd1 = (const float*)d_in[7];
  const float* bd1 = (const float*)d_in[8];
  float* out = (float*)d_out;

  uint8_t* ws = (uint8_t*)d_ws;
  size_t off = 0;
  auto carve = [&](size_t bytes) {
    uint8_t* p = ws + off;
    off += (bytes + 255) & ~(size_t)255;
    return p;
  };
  u16*    A2   = (u16*)carve((size_t)B_SZ * KA2 * 2);
  u16*    xb   = (u16*)carve((size_t)B_SZ * DDATA * 2);
  u16*    W1T  = (u16*)carve((size_t)NJK * DDATA * 2);
  u16*    B2T  = (u16*)carve((size_t)DDATA * KA2 * 2);
  float*  cvp  = (float*)carve((size_t)3 * NJK * 4);
  float*  part = (float*)carve((size_t)SPLITK * B_SZ * DDATA * 4);   // 25.2 MB

  // all pre-GEMM work (gate+acts0+fixup, W1T/cv, B2T, x-cast) in one kernel
  k_front <<<1712, 256, 0, stream>>>(x, We0, be0, bd0, We1, bd1, be1, Wd1, Wd0,
                                     W1T, cvp, B2T, xb, A2);
  // GEMM1 (M=2048,N=4096,K=768): 64x128, proper dbuf, 1024 blocks (3/CU @ 50KB)
  k_gemm<64, 128, 1><<<1024, 256, 0, stream>>>(xb, W1T, DDATA, DDATA,
                                               nullptr, A2, cvp);
  // GEMM2 split-K (M=2048,N=768,K=4352): 64x128, proper dbuf, 768 blocks (3/CU)
  k_gemm<64, 128, 2><<<768, 256, 0, stream>>>(A2, B2T, KA2, KC2,
                                              part, nullptr, nullptr);
  k_reduce<<<1536, 256, 0, stream>>>(part, bd0, out);
}

// Round 10
// 152.902 us; speedup vs baseline: 1.6850x; 1.0511x over previous
//
#include <hip/hip_runtime.h>
#include <hip/hip_bf16.h>
#include <stdint.h>

#define B_SZ   2048
#define DDATA  768
#define NSAE   128
#define NJK    4096   // NSAE*32
#define KA2    4352   // NJK + 128 (acts0) + 128 (gate)
#define SPLITK 4
#define KC2    1088   // KA2 / SPLITK (17 x BK=64)

typedef unsigned short u16;
typedef short bf16x8 __attribute__((ext_vector_type(8)));
typedef float f32x4  __attribute__((ext_vector_type(4)));

static __device__ __forceinline__ u16 f2bf(float f) {
  __hip_bfloat16 h = __float2bfloat16(f);
  return *reinterpret_cast<u16*>(&h);
}

static __device__ __forceinline__ void gload16(const u16* g, u16* l) {
  __builtin_amdgcn_global_load_lds(
      (const __attribute__((address_space(1))) unsigned int*)g,
      (__attribute__((address_space(3))) unsigned int*)l,
      16, 0, 0);
}

// ======== k_front: ALL pre-GEMM work in ONE kernel (R3/R9-verified) ========
// blocks    0..511 : gate/acts0: 4 rows/block, 4 waves split d into 192-chunks
// blocks  512..895 : expert j transpose We1[j]->W1T, dbk seg-split 3x;
//                    cv partials to cvp[seg] (summed in GEMM1 epilogue)
// blocks 896..1711 : B2T build ([W_dec1 ; W_dec0 ; b_dec1]^T), 68 rb x 12 dbk
__global__ __launch_bounds__(256) void k_front(const float* __restrict__ x,
                                               const float* __restrict__ We0,
                                               const float* __restrict__ be0,
                                               const float* __restrict__ bd0,
                                               const float* __restrict__ We1,
                                               const float* __restrict__ bd1,
                                               const float* __restrict__ be1,
                                               const float* __restrict__ Wd1,
                                               const float* __restrict__ Wd0,
                                               u16* __restrict__ W1T,
                                               float* __restrict__ cvp,
                                               u16* __restrict__ B2T,
                                               u16* __restrict__ xb,
                                               u16* __restrict__ A2) {
  __shared__ float smem[6280];                  // 25.1 KB, shared by all branches
  const int bid = blockIdx.x, t = threadIdx.x;
  if (bid < 512) {
    // ---------------- gate branch: rows b0..b0+3 ----------------
    const int b0 = bid * 4;
    float* xs   = smem;                         // [4][768] = x - bd0
    float* part = smem + 3072;                  // [4 waves][4 rows][128]
    float* wqp  = smem + 5120;                  // [4 waves][128] ||We0||^2 partials
    float* xns  = smem + 5632;                  // [4] row norms
#pragma unroll
    for (int i = 0; i < 3; ++i) {
      int idx = t + i * 256;                    // 768 float4
      int r = idx / 192, c4 = idx % 192;
      size_t go = (size_t)(b0 + r) * DDATA + c4 * 4;
      float4 v = *(const float4*)&x[go];
      ushort4 o;
      o.x = f2bf(v.x); o.y = f2bf(v.y); o.z = f2bf(v.z); o.w = f2bf(v.w);
      *(ushort4*)&xb[go] = o;                   // fused x cast for GEMM1
      float4 b4 = *(const float4*)&bd0[c4 * 4];
      v.x -= b4.x; v.y -= b4.y; v.z -= b4.z; v.w -= b4.w;
      *(float4*)&xs[r * DDATA + c4 * 4] = v;
    }
    __syncthreads();
    const int ln = t & 63, w = t >> 6;
    {                                           // row norm: wave w owns row w
      float a = 0.f;
#pragma unroll
      for (int q = 0; q < 12; ++q) { float xv = xs[w * DDATA + ln + q * 64]; a += xv * xv; }
#pragma unroll
      for (int sh = 32; sh; sh >>= 1) a += __shfl_xor(a, sh, 64);
      if (ln == 0) xns[w] = a;
    }
    const int j0 = ln * 2;                      // 2 experts per lane
    float a00=0.f,a01=0.f,a10=0.f,a11=0.f,a20=0.f,a21=0.f,a30=0.f,a31=0.f;
    float wq0=0.f, wq1=0.f;
    const int dbase = w * 192;
    for (int d = dbase; d < dbase + 192; d += 4) {
      float4 xv0 = *(const float4*)&xs[0 * DDATA + d];   // wave-uniform bcast
      float4 xv1 = *(const float4*)&xs[1 * DDATA + d];
      float4 xv2 = *(const float4*)&xs[2 * DDATA + d];
      float4 xv3 = *(const float4*)&xs[3 * DDATA + d];
#pragma unroll
      for (int dd = 0; dd < 4; ++dd) {
        float2 w2 = *(const float2*)&We0[(size_t)(d + dd) * 128 + j0];
        float x0 = ((const float*)&xv0)[dd], x1 = ((const float*)&xv1)[dd];
        float x2 = ((const float*)&xv2)[dd], x3 = ((const float*)&xv3)[dd];
        a00 += x0 * w2.x; a01 += x0 * w2.y;
        a10 += x1 * w2.x; a11 += x1 * w2.y;
        a20 += x2 * w2.x; a21 += x2 * w2.y;
        a30 += x3 * w2.x; a31 += x3 * w2.y;
        wq0 += w2.x * w2.x; wq1 += w2.y * w2.y;
      }
    }
    *(float2*)&part[(w * 4 + 0) * 128 + j0] = make_float2(a00, a01);
    *(float2*)&part[(w * 4 + 1) * 128 + j0] = make_float2(a10, a11);
    *(float2*)&part[(w * 4 + 2) * 128 + j0] = make_float2(a20, a21);
    *(float2*)&part[(w * 4 + 3) * 128 + j0] = make_float2(a30, a31);
    *(float2*)&wqp[w * 128 + j0] = make_float2(wq0, wq1);
    __syncthreads();
    float p0 = be0[j0], p1 = be0[j0 + 1];
    float wn0 = 0.f, wn1 = 0.f;
#pragma unroll
    for (int q = 0; q < 4; ++q) {
      float2 pr = *(const float2*)&part[(q * 4 + w) * 128 + j0];
      p0 += pr.x; p1 += pr.y;
      float2 wr2 = *(const float2*)&wqp[q * 128 + j0];
      wn0 += wr2.x; wn1 += wr2.y;
    }
    const float sx = sqrtf(xns[w]);
    const float tau0 = 1e-4f * sx * sqrtf(wn0);
    const float tau1 = 1e-4f * sx * sqrtf(wn1);
    const int bb = b0 + w;
    const size_t row = (size_t)bb * KA2;
    unsigned pk = (unsigned)f2bf(p0 > 0.f ? p0 : 0.f) |
                  ((unsigned)f2bf(p1 > 0.f ? p1 : 0.f) << 16);
    unsigned gk = (p0 > 0.f ? 0x3F80u : 0u) | (p1 > 0.f ? 0x3F800000u : 0u);
    *(unsigned*)&A2[row + NJK + j0]       = pk;
    *(unsigned*)&A2[row + NJK + 128 + j0] = gk;
    // fp32 sign uncertain -> whole wave cooperates on exact fp64 recompute
#pragma unroll
    for (int c = 0; c < 2; ++c) {
      float pv = c ? p1 : p0;
      float tv = c ? tau1 : tau0;
      unsigned long long mask = __ballot(fabsf(pv) <= tv);
      while (mask) {
        int src = (int)__builtin_ctzll(mask);
        mask &= mask - 1;
        int jj = src * 2 + c;
        double acc = 0.0;
#pragma unroll
        for (int q = 0; q < 12; ++q) {
          int d = ln + q * 64;
          acc += (double)(x[(size_t)bb * DDATA + d] - bd0[d]) *
                 (double)We0[(size_t)d * 128 + jj];
        }
#pragma unroll
        for (int sh = 32; sh; sh >>= 1) acc += __shfl_xor(acc, sh, 64);
        if (ln == src) {
          double pd = acc + (double)be0[jj];
          A2[row + NJK + jj]       = f2bf(pd > 0.0 ? (float)pd : 0.f);
          A2[row + NJK + 128 + jj] = (pd > 0.0) ? (u16)0x3F80 : (u16)0;
        }
      }
    }
  } else if (bid < 896) {
    // ---------------- We1 transpose + cv partials (j, seg) ----------------
    const int e = bid - 512;
    const int j = e & 127, seg = e >> 7;        // seg 0..2 -> dbk seg*4..seg*4+3
    float* ts  = smem;                          // 64*33
    float* bds = smem + 64 * 33;                // 64
    float* red = smem + 64 * 33 + 64;           // 8*32
    const int k = t & 31, g = t >> 5;
    float cacc = 0.f;
    for (int db = seg * 4; db < seg * 4 + 4; ++db) {
      const float* src = We1 + (size_t)j * 24576 + db * 2048;  // 64 d x 32 k
#pragma unroll
      for (int i = 0; i < 8; ++i) {
        int ee = t + i * 256;
        ts[(ee >> 5) * 33 + (ee & 31)] = src[ee];
      }
      if (t < 64) bds[t] = bd1[(size_t)j * DDATA + db * 64 + t];
      __syncthreads();
#pragma unroll
      for (int i = 0; i < 8; ++i) {
        int ee = t + i * 256;
        int kk = ee >> 6, d = ee & 63;
        W1T[(size_t)(j * 32 + kk) * DDATA + db * 64 + d] = f2bf(ts[d * 33 + kk]);
      }
#pragma unroll
      for (int q = 0; q < 8; ++q) {
        int d = g + 8 * q;
        cacc += ts[d * 33 + k] * bds[d];
      }
      __syncthreads();
    }
    red[g * 32 + k] = cacc;
    __syncthreads();
    if (g == 0) {
      float s = 0.f;
#pragma unroll
      for (int q = 0; q < 8; ++q) s += red[q * 32 + k];
      cvp[seg * 4096 + j * 32 + k] = (seg == 0 ? be1[j * 32 + k] : 0.f) - s;
    }
  } else {
    // ---------------- B2T build ----------------
    const int e2 = bid - 896;
    const int rb = e2 / 12, dbk = e2 % 12;
    const float* src; int r0, base;
    if (rb < 64)      { src = Wd1; r0 = rb * 64;        base = 0;    }
    else if (rb < 66) { src = Wd0; r0 = (rb - 64) * 64; base = 4096; }
    else              { src = bd1; r0 = (rb - 66) * 64; base = 4224; }
    const int d0 = dbk * 64;
#pragma unroll
    for (int i = 0; i < 16; ++i) {
      int ee = t + i * 256;
      int ri = ee >> 6, di = ee & 63;
      smem[ri * 65 + di] = src[(size_t)(r0 + ri) * DDATA + d0 + di];
    }
    __syncthreads();
#pragma unroll
    for (int i = 0; i < 16; ++i) {
      int ee = t + i * 256;
      int di = ee >> 6, ri = ee & 63;
      B2T[(size_t)(d0 + di) * KA2 + base + r0 + ri] = f2bf(smem[ri * 65 + di]);
    }
  }
}

// ======== k_gemm1: 256x128 tile, 8 waves, TRUE software pipeline (T3+T4) ========
// 3 LDS buffers, 2-deep prefetch, ONE raw s_barrier per K-step, counted
// s_waitcnt vmcnt(6) (never drains in-loop). Fences per guide rule #18:
// sched_barrier(0) after barrier. Safety argument:
//  - vmcnt(6) waits exactly tile t's 6 gload_lds (per thread; in-order retire);
//    all waves wait before the barrier -> tile t fully in LDS after barrier.
//  - compute is LDS+MFMA only (no VMEM) -> the vmcnt count is exact.
//  - stage(t+2) overwrites buf[(t+2)%3], last read by compute(t-1); every wave
//    finished compute(t-1) before the barrier of step t (MFMAs consume
//    ds_reads in program order) -> no WAR race across the 3 buffers.
//  - epilogue preloads (plain loads) happen AFTER the loop -> don't perturb count.
__global__ __launch_bounds__(512) void k_gemm1(const u16* __restrict__ A,
                                               const u16* __restrict__ Bm,
                                               u16* __restrict__ A2,
                                               const float* __restrict__ cvec) {
  constexpr int BM = 256, BN = 128, BK = 64, NT = DDATA / BK;  // 12
  __shared__ __align__(16) u16 As[3][BM * BK];   // 96 KB
  __shared__ __align__(16) u16 Bs[3][BN * BK];   // 48 KB
  __shared__ u16 gate_s[BM * 4];
  __shared__ float cv_s[BN];
  const int tid = threadIdx.x;
  // 256 blocks = 8 XCD-chunks of 32 (8 by x 4 bx per chunk) -> L2-local panels
  const int h = blockIdx.x;
  const int l = (h & 7) * 32 + (h >> 3);        // bijective: 256 = 8*32
  const int g2 = l >> 5, w = l & 31;
  const int by = w >> 2, bx = (g2 << 2) + (w & 3);
  const u16* Ab = A  + (size_t)(by * BM) * DDATA;
  const u16* Bb = Bm + (size_t)(bx * BN) * DDATA;
  const int wave = tid >> 6, lane = tid & 63;
  const int wr = wave >> 1, wc = wave & 1;      // 4M x 2N wave grid
  const int m0 = wr * 64, n0 = wc * 64;         // per-wave 64x64 output
  const int lm = lane & 15, qd = lane >> 4;

  f32x4 acc[4][4];
  const f32x4 zero = {0.f, 0.f, 0.f, 0.f};
  for (int mi = 0; mi < 4; ++mi)
    for (int ni = 0; ni < 4; ++ni) acc[mi][ni] = zero;

  auto stage = [&](int kt, int buf) {           // 6 gload16 per thread
    const int k0 = kt * BK;
#pragma unroll
    for (int i = 0; i < 4; ++i) {               // A: 256 rows x 8 chunks
      int id = tid + 512 * i;
      int row = id >> 3, u = id & 7;
      gload16(Ab + (size_t)row * DDATA + k0 + ((u ^ (row & 7)) * 8), &As[buf][id * 8]);
    }
#pragma unroll
    for (int i = 0; i < 2; ++i) {               // B: 128 rows x 8 chunks
      int id = tid + 512 * i;
      int row = id >> 3, u = id & 7;
      gload16(Bb + (size_t)row * DDATA + k0 + ((u ^ (row & 7)) * 8), &Bs[buf][id * 8]);
    }
  };
  auto compute = [&](int buf) {
#pragma unroll
    for (int s = 0; s < 2; ++s) {
      const int swz = ((s << 2) + qd) ^ (lm & 7);
      bf16x8 af[4], bfv[4];
#pragma unroll
      for (int mi = 0; mi < 4; ++mi)
        af[mi] = *(const bf16x8*)&As[buf][(m0 + mi * 16 + lm) * BK + swz * 8];
#pragma unroll
      for (int ni = 0; ni < 4; ++ni)
        bfv[ni] = *(const bf16x8*)&Bs[buf][(n0 + ni * 16 + lm) * BK + swz * 8];
#pragma unroll
      for (int mi = 0; mi < 4; ++mi)
#pragma unroll
        for (int ni = 0; ni < 4; ++ni)
          acc[mi][ni] = __builtin_amdgcn_mfma_f32_16x16x32_bf16(af[mi], bfv[ni],
                                                                acc[mi][ni], 0, 0, 0);
    }
  };

  stage(0, 0);
  stage(1, 1);                                  // 12 loads in flight
  for (int t = 0; t < NT; ++t) {
    if (t == NT - 1) asm volatile("s_waitcnt vmcnt(0)" ::: "memory");
    else             asm volatile("s_waitcnt vmcnt(6)" ::: "memory");
    __builtin_amdgcn_s_barrier();               // tile t ready in all waves
    __builtin_amdgcn_sched_barrier(0);          // rule #18: no hoist above
    compute(t % 3);
    __builtin_amdgcn_sched_barrier(0);
    if (t + 2 < NT) stage(t + 2, (t + 2) % 3);  // refill pipeline
  }

  // epilogue data (loaded after the pipeline so vmcnt counting stays exact)
  for (int e = tid; e < BM * 4; e += 512) {
    int r = e >> 2, q = e & 3;
    gate_s[e] = A2[(size_t)(by * BM + r) * KA2 + NJK + 128 + bx * 4 + q];
  }
  for (int e = tid; e < BN; e += 512)
    cv_s[e] = cvec[bx * BN + e] + cvec[4096 + bx * BN + e] + cvec[8192 + bx * BN + e];
  __syncthreads();

  const int rb = qd * 4;
#pragma unroll
  for (int mi = 0; mi < 4; ++mi) {
#pragma unroll
    for (int ni = 0; ni < 4; ++ni) {
#pragma unroll
      for (int r = 0; r < 4; ++r) {
        int ml = m0 + mi * 16 + rb + r;
        int nl = n0 + ni * 16 + lm;
        int gm = by * BM + ml;
        int gn = bx * BN + nl;
        float v = acc[mi][ni][r];
        v += cv_s[nl];
        v = v > 0.f ? v : 0.f;
        u16 gbit = gate_s[ml * 4 + (nl >> 5)];
        v = gbit ? v : 0.f;
        float vn = __shfl_xor(v, 1, 64);        // pack even/odd columns
        if ((lm & 1) == 0) {
          unsigned pk = (unsigned)f2bf(v) | ((unsigned)f2bf(vn) << 16);
          *(unsigned*)&A2[(size_t)gm * KA2 + gn] = pk;
        }
      }
    }
  }
}

// ------ k_gemm2: split-K partials, proper dbuf + __syncthreads (R9-verified) ------
__global__ __launch_bounds__(256) void k_gemm2(const u16* __restrict__ A,
                                               const u16* __restrict__ Bm,
                                               float* __restrict__ outF) {
  constexpr int BM = 64, BN = 128;
  __shared__ __align__(16) u16 As[2][BM * 64];
  __shared__ __align__(16) u16 Bs[2][BN * 64];
  const int tid = threadIdx.x;
  const int h = blockIdx.x;
  const int l = (h & 7) * 96 + (h >> 3);        // bijective: 768 = 8*96
  const int bx = l >> 7; const int r2 = l & 127;
  const int bz = r2 >> 5, by = r2 & 31;
  const int kbase = bz * KC2;
  const u16* Ab = A  + (size_t)(by * BM) * KA2;
  const u16* Bb = Bm + (size_t)(bx * BN) * KA2;
  const int wave = tid >> 6, lane = tid & 63;
  const int wr = wave >> 1, wc = wave & 1;
  const int m0 = wr * (BM / 2), n0 = wc * (BN / 2);
  const int lm = lane & 15, qd = lane >> 4;

  f32x4 acc[2][4];
  const f32x4 zero = {0.f, 0.f, 0.f, 0.f};
  for (int mi = 0; mi < 2; ++mi)
    for (int ni = 0; ni < 4; ++ni) acc[mi][ni] = zero;

  auto stage = [&](int kt, int buf) {
    const int k0 = kbase + kt * 64;
#pragma unroll
    for (int i = 0; i < BM / 32; ++i) {
      int id = tid + 256 * i;
      int row = id >> 3, u = id & 7;
      gload16(Ab + (size_t)row * KA2 + k0 + ((u ^ (row & 7)) * 8), &As[buf][id * 8]);
    }
#pragma unroll
    for (int i = 0; i < BN / 32; ++i) {
      int id = tid + 256 * i;
      int row = id >> 3, u = id & 7;
      gload16(Bb + (size_t)row * KA2 + k0 + ((u ^ (row & 7)) * 8), &Bs[buf][id * 8]);
    }
  };
  auto compute = [&](int buf) {
#pragma unroll
    for (int s = 0; s < 2; ++s) {
      const int swz = ((s << 2) + qd) ^ (lm & 7);
      bf16x8 af[2], bfv[4];
#pragma unroll
      for (int mi = 0; mi < 2; ++mi)
        af[mi] = *(const bf16x8*)&As[buf][(m0 + mi * 16 + lm) * 64 + swz * 8];
#pragma unroll
      for (int ni = 0; ni < 4; ++ni)
        bfv[ni] = *(const bf16x8*)&Bs[buf][(n0 + ni * 16 + lm) * 64 + swz * 8];
#pragma unroll
      for (int mi = 0; mi < 2; ++mi)
#pragma unroll
        for (int ni = 0; ni < 4; ++ni)
          acc[mi][ni] = __builtin_amdgcn_mfma_f32_16x16x32_bf16(af[mi], bfv[ni],
                                                                acc[mi][ni], 0, 0, 0);
    }
  };

  const int NT = KC2 / 64;                      // 17
  stage(0, 0);
  __syncthreads();
  int cur = 0;
  for (int t = 0; t < NT; ++t) {
    if (t + 1 < NT) stage(t + 1, cur ^ 1);
    compute(cur);
    __syncthreads();
    cur ^= 1;
  }

  const int rb = qd * 4;
#pragma unroll
  for (int mi = 0; mi < 2; ++mi)
#pragma unroll
    for (int ni = 0; ni < 4; ++ni)
#pragma unroll
      for (int r = 0; r < 4; ++r) {
        int ml = m0 + mi * 16 + rb + r;
        int nl = n0 + ni * 16 + lm;
        int gm = by * BM + ml;
        int gn = bx * BN + nl;
        outF[((size_t)bz * B_SZ + gm) * DDATA + gn] = acc[mi][ni][r];
      }
}

// ---------------- reduce split-K partials + bias ----------------
__global__ __launch_bounds__(256) void k_reduce(const float* __restrict__ part,
                                                const float* __restrict__ bias,
                                                float* __restrict__ out) {
  const int N4 = B_SZ * DDATA / 4;
  int i = blockIdx.x * 256 + threadIdx.x;
  const float4* p4 = (const float4*)part;
  float4 s = p4[i];
#pragma unroll
  for (int z = 1; z < SPLITK; ++z) {
    float4 t = p4[i + z * N4];
    s.x += t.x; s.y += t.y; s.z += t.z; s.w += t.w;
  }
  float4 b = ((const float4*)bias)[i % (DDATA / 4)];
  s.x += b.x; s.y += b.y; s.z += b.z; s.w += b.w;
  ((float4*)out)[i] = s;
}

extern "C" void kernel_launch(void* const* d_in, const int* in_sizes, int n_in,
                              void* d_out, int out_size, void* d_ws, size_t ws_size,
                              hipStream_t stream) {
  const float* x   = (const float*)d_in[0];
  const float* We0 = (const float*)d_in[1];
  const float* be0 = (const float*)d_in[2];
  const float* Wd0 = (const float*)d_in[3];
  const float* bd0 = (const float*)d_in[4];
  const float* We1 = (const float*)d_in[5];
  const float* be1 = (const float*)d_in[6];
  const float* Wd1 = (const float*)d_in[7];
  const float* bd1 = (const float*)d_in[8];
  float* out = (float*)d_out;

  uint8_t* ws = (uint8_t*)d_ws;
  size_t off = 0;
  auto carve = [&](size_t bytes) {
    uint8_t* p = ws + off;
    off += (bytes + 255) & ~(size_t)255;
    return p;
  };
  u16*    A2   = (u16*)carve((size_t)B_SZ * KA2 * 2);
  u16*    xb   = (u16*)carve((size_t)B_SZ * DDATA * 2);
  u16*    W1T  = (u16*)carve((size_t)NJK * DDATA * 2);
  u16*    B2T  = (u16*)carve((size_t)DDATA * KA2 * 2);
  float*  cvp  = (float*)carve((size_t)3 * NJK * 4);
  float*  part = (float*)carve((size_t)SPLITK * B_SZ * DDATA * 4);   // 25.2 MB

  // all pre-GEMM work (gate+acts0+fixup, W1T/cv, B2T, x-cast) in one kernel
  k_front <<<1712, 256, 0, stream>>>(x, We0, be0, bd0, We1, bd1, be1, Wd1, Wd0,
                                     W1T, cvp, B2T, xb, A2);
  // GEMM1 (M=2048,N=4096,K=768): 256x128 tile, 8 waves, 3-buf counted-vmcnt
  // pipeline -> 256 blocks (1/CU, 144KB LDS)
  k_gemm1<<<256, 512, 0, stream>>>(xb, W1T, A2, cvp);
  // GEMM2 split-K (M=2048,N=768,K=4352): 64x128, proper dbuf, 768 blocks (3/CU)
  k_gemm2<<<768, 256, 0, stream>>>(A2, B2T, part);
  k_reduce<<<1536, 256, 0, stream>>>(part, bd0, out);
}

// Round 11
// 150.187 us; speedup vs baseline: 1.7155x; 1.0181x over previous
//
#include <hip/hip_runtime.h>
#include <hip/hip_bf16.h>
#include <stdint.h>

#define B_SZ   2048
#define DDATA  768
#define NSAE   128
#define NJK    4096   // NSAE*32
#define KA2    4352   // NJK + 128 (acts0) + 128 (gate)
#define SPLITK 4
#define KC2    1088   // KA2 / SPLITK (17 x BK=64)

typedef unsigned short u16;
typedef short bf16x8 __attribute__((ext_vector_type(8)));
typedef float f32x4  __attribute__((ext_vector_type(4)));

static __device__ __forceinline__ u16 f2bf(float f) {
  __hip_bfloat16 h = __float2bfloat16(f);
  return *reinterpret_cast<u16*>(&h);
}

static __device__ __forceinline__ void gload16(const u16* g, u16* l) {
  __builtin_amdgcn_global_load_lds(
      (const __attribute__((address_space(1))) unsigned int*)g,
      (__attribute__((address_space(3))) unsigned int*)l,
      16, 0, 0);
}

// ======== k_front: ALL pre-GEMM work in ONE kernel (R3/R9/R10-verified) ========
// blocks    0..511 : gate/acts0: 4 rows/block, 4 waves split d into 192-chunks
// blocks  512..895 : expert j transpose We1[j]->W1T, dbk seg-split 3x;
//                    cv partials to cvp[seg] (summed in GEMM1 epilogue)
// blocks 896..1711 : B2T build ([W_dec1 ; W_dec0 ; b_dec1]^T), 68 rb x 12 dbk
__global__ __launch_bounds__(256) void k_front(const float* __restrict__ x,
                                               const float* __restrict__ We0,
                                               const float* __restrict__ be0,
                                               const float* __restrict__ bd0,
                                               const float* __restrict__ We1,
                                               const float* __restrict__ bd1,
                                               const float* __restrict__ be1,
                                               const float* __restrict__ Wd1,
                                               const float* __restrict__ Wd0,
                                               u16* __restrict__ W1T,
                                               float* __restrict__ cvp,
                                               u16* __restrict__ B2T,
                                               u16* __restrict__ xb,
                                               u16* __restrict__ A2) {
  __shared__ float smem[6280];                  // 25.1 KB, shared by all branches
  const int bid = blockIdx.x, t = threadIdx.x;
  if (bid < 512) {
    // ---------------- gate branch: rows b0..b0+3 ----------------
    const int b0 = bid * 4;
    float* xs   = smem;                         // [4][768] = x - bd0
    float* part = smem + 3072;                  // [4 waves][4 rows][128]
    float* wqp  = smem + 5120;                  // [4 waves][128] ||We0||^2 partials
    float* xns  = smem + 5632;                  // [4] row norms
#pragma unroll
    for (int i = 0; i < 3; ++i) {
      int idx = t + i * 256;                    // 768 float4
      int r = idx / 192, c4 = idx % 192;
      size_t go = (size_t)(b0 + r) * DDATA + c4 * 4;
      float4 v = *(const float4*)&x[go];
      ushort4 o;
      o.x = f2bf(v.x); o.y = f2bf(v.y); o.z = f2bf(v.z); o.w = f2bf(v.w);
      *(ushort4*)&xb[go] = o;                   // fused x cast for GEMM1
      float4 b4 = *(const float4*)&bd0[c4 * 4];
      v.x -= b4.x; v.y -= b4.y; v.z -= b4.z; v.w -= b4.w;
      *(float4*)&xs[r * DDATA + c4 * 4] = v;
    }
    __syncthreads();
    const int ln = t & 63, w = t >> 6;
    {                                           // row norm: wave w owns row w
      float a = 0.f;
#pragma unroll
      for (int q = 0; q < 12; ++q) { float xv = xs[w * DDATA + ln + q * 64]; a += xv * xv; }
#pragma unroll
      for (int sh = 32; sh; sh >>= 1) a += __shfl_xor(a, sh, 64);
      if (ln == 0) xns[w] = a;
    }
    const int j0 = ln * 2;                      // 2 experts per lane
    float a00=0.f,a01=0.f,a10=0.f,a11=0.f,a20=0.f,a21=0.f,a30=0.f,a31=0.f;
    float wq0=0.f, wq1=0.f;
    const int dbase = w * 192;
    for (int d = dbase; d < dbase + 192; d += 4) {
      float4 xv0 = *(const float4*)&xs[0 * DDATA + d];   // wave-uniform bcast
      float4 xv1 = *(const float4*)&xs[1 * DDATA + d];
      float4 xv2 = *(const float4*)&xs[2 * DDATA + d];
      float4 xv3 = *(const float4*)&xs[3 * DDATA + d];
#pragma unroll
      for (int dd = 0; dd < 4; ++dd) {
        float2 w2 = *(const float2*)&We0[(size_t)(d + dd) * 128 + j0];
        float x0 = ((const float*)&xv0)[dd], x1 = ((const float*)&xv1)[dd];
        float x2 = ((const float*)&xv2)[dd], x3 = ((const float*)&xv3)[dd];
        a00 += x0 * w2.x; a01 += x0 * w2.y;
        a10 += x1 * w2.x; a11 += x1 * w2.y;
        a20 += x2 * w2.x; a21 += x2 * w2.y;
        a30 += x3 * w2.x; a31 += x3 * w2.y;
        wq0 += w2.x * w2.x; wq1 += w2.y * w2.y;
      }
    }
    *(float2*)&part[(w * 4 + 0) * 128 + j0] = make_float2(a00, a01);
    *(float2*)&part[(w * 4 + 1) * 128 + j0] = make_float2(a10, a11);
    *(float2*)&part[(w * 4 + 2) * 128 + j0] = make_float2(a20, a21);
    *(float2*)&part[(w * 4 + 3) * 128 + j0] = make_float2(a30, a31);
    *(float2*)&wqp[w * 128 + j0] = make_float2(wq0, wq1);
    __syncthreads();
    float p0 = be0[j0], p1 = be0[j0 + 1];
    float wn0 = 0.f, wn1 = 0.f;
#pragma unroll
    for (int q = 0; q < 4; ++q) {
      float2 pr = *(const float2*)&part[(q * 4 + w) * 128 + j0];
      p0 += pr.x; p1 += pr.y;
      float2 wr2 = *(const float2*)&wqp[q * 128 + j0];
      wn0 += wr2.x; wn1 += wr2.y;
    }
    const float sx = sqrtf(xns[w]);
    const float tau0 = 1e-4f * sx * sqrtf(wn0);
    const float tau1 = 1e-4f * sx * sqrtf(wn1);
    const int bb = b0 + w;
    const size_t row = (size_t)bb * KA2;
    unsigned pk = (unsigned)f2bf(p0 > 0.f ? p0 : 0.f) |
                  ((unsigned)f2bf(p1 > 0.f ? p1 : 0.f) << 16);
    unsigned gk = (p0 > 0.f ? 0x3F80u : 0u) | (p1 > 0.f ? 0x3F800000u : 0u);
    *(unsigned*)&A2[row + NJK + j0]       = pk;
    *(unsigned*)&A2[row + NJK + 128 + j0] = gk;
    // fp32 sign uncertain -> whole wave cooperates on exact fp64 recompute
#pragma unroll
    for (int c = 0; c < 2; ++c) {
      float pv = c ? p1 : p0;
      float tv = c ? tau1 : tau0;
      unsigned long long mask = __ballot(fabsf(pv) <= tv);
      while (mask) {
        int src = (int)__builtin_ctzll(mask);
        mask &= mask - 1;
        int jj = src * 2 + c;
        double acc = 0.0;
#pragma unroll
        for (int q = 0; q < 12; ++q) {
          int d = ln + q * 64;
          acc += (double)(x[(size_t)bb * DDATA + d] - bd0[d]) *
                 (double)We0[(size_t)d * 128 + jj];
        }
#pragma unroll
        for (int sh = 32; sh; sh >>= 1) acc += __shfl_xor(acc, sh, 64);
        if (ln == src) {
          double pd = acc + (double)be0[jj];
          A2[row + NJK + jj]       = f2bf(pd > 0.0 ? (float)pd : 0.f);
          A2[row + NJK + 128 + jj] = (pd > 0.0) ? (u16)0x3F80 : (u16)0;
        }
      }
    }
  } else if (bid < 896) {
    // ---------------- We1 transpose + cv partials (j, seg) ----------------
    const int e = bid - 512;
    const int j = e & 127, seg = e >> 7;        // seg 0..2 -> dbk seg*4..seg*4+3
    float* ts  = smem;                          // 64*33
    float* bds = smem + 64 * 33;                // 64
    float* red = smem + 64 * 33 + 64;           // 8*32
    const int k = t & 31, g = t >> 5;
    float cacc = 0.f;
    for (int db = seg * 4; db < seg * 4 + 4; ++db) {
      const float* src = We1 + (size_t)j * 24576 + db * 2048;  // 64 d x 32 k
#pragma unroll
      for (int i = 0; i < 8; ++i) {
        int ee = t + i * 256;
        ts[(ee >> 5) * 33 + (ee & 31)] = src[ee];
      }
      if (t < 64) bds[t] = bd1[(size_t)j * DDATA + db * 64 + t];
      __syncthreads();
#pragma unroll
      for (int i = 0; i < 8; ++i) {
        int ee = t + i * 256;
        int kk = ee >> 6, d = ee & 63;
        W1T[(size_t)(j * 32 + kk) * DDATA + db * 64 + d] = f2bf(ts[d * 33 + kk]);
      }
#pragma unroll
      for (int q = 0; q < 8; ++q) {
        int d = g + 8 * q;
        cacc += ts[d * 33 + k] * bds[d];
      }
      __syncthreads();
    }
    red[g * 32 + k] = cacc;
    __syncthreads();
    if (g == 0) {
      float s = 0.f;
#pragma unroll
      for (int q = 0; q < 8; ++q) s += red[q * 32 + k];
      cvp[seg * 4096 + j * 32 + k] = (seg == 0 ? be1[j * 32 + k] : 0.f) - s;
    }
  } else {
    // ---------------- B2T build ----------------
    const int e2 = bid - 896;
    const int rb = e2 / 12, dbk = e2 % 12;
    const float* src; int r0, base;
    if (rb < 64)      { src = Wd1; r0 = rb * 64;        base = 0;    }
    else if (rb < 66) { src = Wd0; r0 = (rb - 64) * 64; base = 4096; }
    else              { src = bd1; r0 = (rb - 66) * 64; base = 4224; }
    const int d0 = dbk * 64;
#pragma unroll
    for (int i = 0; i < 16; ++i) {
      int ee = t + i * 256;
      int ri = ee >> 6, di = ee & 63;
      smem[ri * 65 + di] = src[(size_t)(r0 + ri) * DDATA + d0 + di];
    }
    __syncthreads();
#pragma unroll
    for (int i = 0; i < 16; ++i) {
      int ee = t + i * 256;
      int di = ee >> 6, ri = ee & 63;
      B2T[(size_t)(d0 + di) * KA2 + base + r0 + ri] = f2bf(smem[ri * 65 + di]);
    }
  }
}

// ======== k_gemm1: 256x128 tile, 8 waves, pipelined (R10-VERIFIED, unchanged) ========
__global__ __launch_bounds__(512) void k_gemm1(const u16* __restrict__ A,
                                               const u16* __restrict__ Bm,
                                               u16* __restrict__ A2,
                                               const float* __restrict__ cvec) {
  constexpr int BM = 256, BN = 128, BK = 64, NT = DDATA / BK;  // 12
  __shared__ __align__(16) u16 As[3][BM * BK];   // 96 KB
  __shared__ __align__(16) u16 Bs[3][BN * BK];   // 48 KB
  __shared__ u16 gate_s[BM * 4];
  __shared__ float cv_s[BN];
  const int tid = threadIdx.x;
  const int h = blockIdx.x;
  const int l = (h & 7) * 32 + (h >> 3);        // bijective: 256 = 8*32
  const int g2 = l >> 5, w = l & 31;
  const int by = w >> 2, bx = (g2 << 2) + (w & 3);
  const u16* Ab = A  + (size_t)(by * BM) * DDATA;
  const u16* Bb = Bm + (size_t)(bx * BN) * DDATA;
  const int wave = tid >> 6, lane = tid & 63;
  const int wr = wave >> 1, wc = wave & 1;      // 4M x 2N wave grid
  const int m0 = wr * 64, n0 = wc * 64;         // per-wave 64x64 output
  const int lm = lane & 15, qd = lane >> 4;

  f32x4 acc[4][4];
  const f32x4 zero = {0.f, 0.f, 0.f, 0.f};
  for (int mi = 0; mi < 4; ++mi)
    for (int ni = 0; ni < 4; ++ni) acc[mi][ni] = zero;

  auto stage = [&](int kt, int buf) {           // 6 gload16 per thread
    const int k0 = kt * BK;
#pragma unroll
    for (int i = 0; i < 4; ++i) {               // A: 256 rows x 8 chunks
      int id = tid + 512 * i;
      int row = id >> 3, u = id & 7;
      gload16(Ab + (size_t)row * DDATA + k0 + ((u ^ (row & 7)) * 8), &As[buf][id * 8]);
    }
#pragma unroll
    for (int i = 0; i < 2; ++i) {               // B: 128 rows x 8 chunks
      int id = tid + 512 * i;
      int row = id >> 3, u = id & 7;
      gload16(Bb + (size_t)row * DDATA + k0 + ((u ^ (row & 7)) * 8), &Bs[buf][id * 8]);
    }
  };
  auto compute = [&](int buf) {
#pragma unroll
    for (int s = 0; s < 2; ++s) {
      const int swz = ((s << 2) + qd) ^ (lm & 7);
      bf16x8 af[4], bfv[4];
#pragma unroll
      for (int mi = 0; mi < 4; ++mi)
        af[mi] = *(const bf16x8*)&As[buf][(m0 + mi * 16 + lm) * BK + swz * 8];
#pragma unroll
      for (int ni = 0; ni < 4; ++ni)
        bfv[ni] = *(const bf16x8*)&Bs[buf][(n0 + ni * 16 + lm) * BK + swz * 8];
#pragma unroll
      for (int mi = 0; mi < 4; ++mi)
#pragma unroll
        for (int ni = 0; ni < 4; ++ni)
          acc[mi][ni] = __builtin_amdgcn_mfma_f32_16x16x32_bf16(af[mi], bfv[ni],
                                                                acc[mi][ni], 0, 0, 0);
    }
  };

  stage(0, 0);
  stage(1, 1);                                  // 12 loads in flight
  for (int t = 0; t < NT; ++t) {
    if (t == NT - 1) asm volatile("s_waitcnt vmcnt(0)" ::: "memory");
    else             asm volatile("s_waitcnt vmcnt(6)" ::: "memory");
    __builtin_amdgcn_s_barrier();               // tile t ready in all waves
    __builtin_amdgcn_sched_barrier(0);          // rule #18: no hoist above
    compute(t % 3);
    __builtin_amdgcn_sched_barrier(0);
    if (t + 2 < NT) stage(t + 2, (t + 2) % 3);  // refill pipeline
  }

  // epilogue data (loaded after the pipeline so vmcnt counting stays exact)
  for (int e = tid; e < BM * 4; e += 512) {
    int r = e >> 2, q = e & 3;
    gate_s[e] = A2[(size_t)(by * BM + r) * KA2 + NJK + 128 + bx * 4 + q];
  }
  for (int e = tid; e < BN; e += 512)
    cv_s[e] = cvec[bx * BN + e] + cvec[4096 + bx * BN + e] + cvec[8192 + bx * BN + e];
  __syncthreads();

  const int rb = qd * 4;
#pragma unroll
  for (int mi = 0; mi < 4; ++mi) {
#pragma unroll
    for (int ni = 0; ni < 4; ++ni) {
#pragma unroll
      for (int r = 0; r < 4; ++r) {
        int ml = m0 + mi * 16 + rb + r;
        int nl = n0 + ni * 16 + lm;
        int gm = by * BM + ml;
        int gn = bx * BN + nl;
        float v = acc[mi][ni][r];
        v += cv_s[nl];
        v = v > 0.f ? v : 0.f;
        u16 gbit = gate_s[ml * 4 + (nl >> 5)];
        v = gbit ? v : 0.f;
        float vn = __shfl_xor(v, 1, 64);        // pack even/odd columns
        if ((lm & 1) == 0) {
          unsigned pk = (unsigned)f2bf(v) | ((unsigned)f2bf(vn) << 16);
          *(unsigned*)&A2[(size_t)gm * KA2 + gn] = pk;
        }
      }
    }
  }
}

// ======== k_gemm2: SAME verified pipeline, ported to split-K (M=2048,N=768) ========
// 256x128 tile, 8 waves, 3 buffers, counted vmcnt(6) (6 gload16/thread,
// identical count to k_gemm1), one raw barrier + sched_barrier(0) per step.
// NT=17 (KC2/64); epilogue = plain fp32 partial store (simpler than G1's).
// Grid 192 = 8 by x 6 bx x 4 bz; XCD-chunked (24 blocks/XCD).
__global__ __launch_bounds__(512) void k_gemm2(const u16* __restrict__ A,
                                               const u16* __restrict__ Bm,
                                               float* __restrict__ outF) {
  constexpr int BM = 256, BN = 128, BK = 64, NT = KC2 / BK;    // 17
  __shared__ __align__(16) u16 As[3][BM * BK];   // 96 KB
  __shared__ __align__(16) u16 Bs[3][BN * BK];   // 48 KB
  const int tid = threadIdx.x;
  const int h = blockIdx.x;
  const int l = (h & 7) * 24 + (h >> 3);        // bijective: 192 = 8*24
  const int bx = l >> 5;                        // [0,6): 32 blocks per bx
  const int r2 = l & 31;
  const int by = r2 >> 2, bz = r2 & 3;          // by [0,8), bz [0,4)
  const int kbase = bz * KC2;
  const u16* Ab = A  + (size_t)(by * BM) * KA2;
  const u16* Bb = Bm + (size_t)(bx * BN) * KA2;
  const int wave = tid >> 6, lane = tid & 63;
  const int wr = wave >> 1, wc = wave & 1;      // 4M x 2N wave grid
  const int m0 = wr * 64, n0 = wc * 64;
  const int lm = lane & 15, qd = lane >> 4;

  f32x4 acc[4][4];
  const f32x4 zero = {0.f, 0.f, 0.f, 0.f};
  for (int mi = 0; mi < 4; ++mi)
    for (int ni = 0; ni < 4; ++ni) acc[mi][ni] = zero;

  auto stage = [&](int kt, int buf) {           // 6 gload16 per thread
    const int k0 = kbase + kt * BK;
#pragma unroll
    for (int i = 0; i < 4; ++i) {               // A: 256 rows x 8 chunks
      int id = tid + 512 * i;
      int row = id >> 3, u = id & 7;
      gload16(Ab + (size_t)row * KA2 + k0 + ((u ^ (row & 7)) * 8), &As[buf][id * 8]);
    }
#pragma unroll
    for (int i = 0; i < 2; ++i) {               // B: 128 rows x 8 chunks
      int id = tid + 512 * i;
      int row = id >> 3, u = id & 7;
      gload16(Bb + (size_t)row * KA2 + k0 + ((u ^ (row & 7)) * 8), &Bs[buf][id * 8]);
    }
  };
  auto compute = [&](int buf) {
#pragma unroll
    for (int s = 0; s < 2; ++s) {
      const int swz = ((s << 2) + qd) ^ (lm & 7);
      bf16x8 af[4], bfv[4];
#pragma unroll
      for (int mi = 0; mi < 4; ++mi)
        af[mi] = *(const bf16x8*)&As[buf][(m0 + mi * 16 + lm) * BK + swz * 8];
#pragma unroll
      for (int ni = 0; ni < 4; ++ni)
        bfv[ni] = *(const bf16x8*)&Bs[buf][(n0 + ni * 16 + lm) * BK + swz * 8];
#pragma unroll
      for (int mi = 0; mi < 4; ++mi)
#pragma unroll
        for (int ni = 0; ni < 4; ++ni)
          acc[mi][ni] = __builtin_amdgcn_mfma_f32_16x16x32_bf16(af[mi], bfv[ni],
                                                                acc[mi][ni], 0, 0, 0);
    }
  };

  stage(0, 0);
  stage(1, 1);                                  // 12 loads in flight
  for (int t = 0; t < NT; ++t) {
    if (t == NT - 1) asm volatile("s_waitcnt vmcnt(0)" ::: "memory");
    else             asm volatile("s_waitcnt vmcnt(6)" ::: "memory");
    __builtin_amdgcn_s_barrier();               // tile t ready in all waves
    __builtin_amdgcn_sched_barrier(0);          // rule #18: no hoist above
    compute(t % 3);
    __builtin_amdgcn_sched_barrier(0);
    if (t + 2 < NT) stage(t + 2, (t + 2) % 3);  // refill pipeline
  }

  const int rb = qd * 4;
#pragma unroll
  for (int mi = 0; mi < 4; ++mi)
#pragma unroll
    for (int ni = 0; ni < 4; ++ni)
#pragma unroll
      for (int r = 0; r < 4; ++r) {
        int ml = m0 + mi * 16 + rb + r;
        int nl = n0 + ni * 16 + lm;
        int gm = by * BM + ml;
        int gn = bx * BN + nl;
        outF[((size_t)bz * B_SZ + gm) * DDATA + gn] = acc[mi][ni][r];
      }
}

// ---------------- reduce split-K partials + bias ----------------
__global__ __launch_bounds__(256) void k_reduce(const float* __restrict__ part,
                                                const float* __restrict__ bias,
                                                float* __restrict__ out) {
  const int N4 = B_SZ * DDATA / 4;
  int i = blockIdx.x * 256 + threadIdx.x;
  const float4* p4 = (const float4*)part;
  float4 s = p4[i];
#pragma unroll
  for (int z = 1; z < SPLITK; ++z) {
    float4 t = p4[i + z * N4];
    s.x += t.x; s.y += t.y; s.z += t.z; s.w += t.w;
  }
  float4 b = ((const float4*)bias)[i % (DDATA / 4)];
  s.x += b.x; s.y += b.y; s.z += b.z; s.w += b.w;
  ((float4*)out)[i] = s;
}

extern "C" void kernel_launch(void* const* d_in, const int* in_sizes, int n_in,
                              void* d_out, int out_size, void* d_ws, size_t ws_size,
                              hipStream_t stream) {
  const float* x   = (const float*)d_in[0];
  const float* We0 = (const float*)d_in[1];
  const float* be0 = (const float*)d_in[2];
  const float* Wd0 = (const float*)d_in[3];
  const float* bd0 = (const float*)d_in[4];
  const float* We1 = (const float*)d_in[5];
  const float* be1 = (const float*)d_in[6];
  const float* Wd1 = (const float*)d_in[7];
  const float* bd1 = (const float*)d_in[8];
  float* out = (float*)d_out;

  uint8_t* ws = (uint8_t*)d_ws;
  size_t off = 0;
  auto carve = [&](size_t bytes) {
    uint8_t* p = ws + off;
    off += (bytes + 255) & ~(size_t)255;
    return p;
  };
  u16*    A2   = (u16*)carve((size_t)B_SZ * KA2 * 2);
  u16*    xb   = (u16*)carve((size_t)B_SZ * DDATA * 2);
  u16*    W1T  = (u16*)carve((size_t)NJK * DDATA * 2);
  u16*    B2T  = (u16*)carve((size_t)DDATA * KA2 * 2);
  float*  cvp  = (float*)carve((size_t)3 * NJK * 4);
  float*  part = (float*)carve((size_t)SPLITK * B_SZ * DDATA * 4);   // 25.2 MB

  // all pre-GEMM work (gate+acts0+fixup, W1T/cv, B2T, x-cast) in one kernel
  k_front <<<1712, 256, 0, stream>>>(x, We0, be0, bd0, We1, bd1, be1, Wd1, Wd0,
                                     W1T, cvp, B2T, xb, A2);
  // GEMM1 (M=2048,N=4096,K=768): 256x128, 8-wave counted-vmcnt pipeline (R10)
  k_gemm1<<<256, 512, 0, stream>>>(xb, W1T, A2, cvp);
  // GEMM2 split-K (M=2048,N=768,K=4352): same pipeline, 192 blocks, NT=17
  k_gemm2<<<192, 512, 0, stream>>>(A2, B2T, part);
  k_reduce<<<1536, 256, 0, stream>>>(part, bd0, out);
}